// Round 4
// baseline (1191.004 us; speedup 1.0000x reference)
//
#include <hip/hip_runtime.h>
#include <hip/hip_bf16.h>

#define HH 192
#define WW 192
#define NWIN 12
#define WSZ 16
#define OWSZ 24
#define PADK 4
#define NQ1 256      // WS*WS
#define NKV1 576     // OWS*OWS
#define C2K 64
#define H2K 4
#define HD 16        // head dim
#define SCALE_F 0.25f
#define NTOK (HH*WW)

typedef __hip_bfloat16 bf16;

// acc[0..15] += s * w[0..15]  (w 16B-aligned)
__device__ __forceinline__ void axpy16(float* acc, float s, const float* w)
{
    const float4* wp = (const float4*)w;
    float4 w0 = wp[0], w1 = wp[1], w2 = wp[2], w3 = wp[3];
    acc[0]  += s * w0.x; acc[1]  += s * w0.y; acc[2]  += s * w0.z; acc[3]  += s * w0.w;
    acc[4]  += s * w1.x; acc[5]  += s * w1.y; acc[6]  += s * w1.z; acc[7]  += s * w1.w;
    acc[8]  += s * w2.x; acc[9]  += s * w2.y; acc[10] += s * w2.z; acc[11] += s * w2.w;
    acc[12] += s * w3.x; acc[13] += s * w3.y; acc[14] += s * w3.z; acc[15] += s * w3.w;
}

// returns dot(q[0..15], k[0..15])
__device__ __forceinline__ float dot16(const float* q, const float* k)
{
    const float4* kp = (const float4*)k;
    float4 k0 = kp[0], k1 = kp[1], k2 = kp[2], k3 = kp[3];
    return q[0]*k0.x + q[1]*k0.y + q[2]*k0.z + q[3]*k0.w
         + q[4]*k1.x + q[5]*k1.y + q[6]*k1.z + q[7]*k1.w
         + q[8]*k2.x + q[9]*k2.y + q[10]*k2.z + q[11]*k2.w
         + q[12]*k3.x + q[13]*k3.y + q[14]*k3.z + q[15]*k3.w;
}

// ---------------- LayerNorm: one wave per 128-ch row ----------------
__launch_bounds__(256)
__global__ void ln_kernel(const float* __restrict__ in, int is, int io,
                          float* __restrict__ out, int os, int oo,
                          const float* __restrict__ g, const float* __restrict__ b,
                          int M)
{
    int row = blockIdx.x * 4 + (threadIdx.x >> 6);
    if (row >= M) return;
    int lane = threadIdx.x & 63;
    const float* p = in + (size_t)row * is + io;
    float v0 = p[lane * 2], v1 = p[lane * 2 + 1];
    float s = v0 + v1, sq = v0 * v0 + v1 * v1;
#pragma unroll
    for (int o = 32; o > 0; o >>= 1) { s += __shfl_xor(s, o); sq += __shfl_xor(sq, o); }
    float mu  = s * 0.0078125f;
    float var = sq * 0.0078125f - mu * mu;
    float inv = 1.0f / sqrtf(var + 1e-5f);
    float* q = out + (size_t)row * os + oo;
    q[lane * 2]     = (v0 - mu) * inv * g[lane * 2]     + b[lane * 2];
    q[lane * 2 + 1] = (v1 - mu) * inv * g[lane * 2 + 1] + b[lane * 2 + 1];
}

// ---------------- combined projection weight ----------------
// Wcomb[128][384]: cols 0:64 q1 (rows=xa 0:63), 64:192 kv1 (rows=xb 64:127),
//                  192:256 q2 (rows=xb), 256:384 kv2 (rows=xa). Zeros elsewhere.
__global__ void wcomb_kernel(const float* __restrict__ q1_w, const float* __restrict__ kv1_w,
                             const float* __restrict__ q2_w, const float* __restrict__ kv2_w,
                             float* __restrict__ W)
{
    int idx = blockIdx.x * 256 + threadIdx.x;
    if (idx >= 128 * 384) return;
    int r = idx / 384, c = idx % 384;
    float v = 0.f;
    if (c < 64)       { if (r < 64)  v = q1_w[r * 64 + c]; }
    else if (c < 192) { if (r >= 64) v = kv1_w[(r - 64) * 128 + (c - 64)]; }
    else if (c < 256) { if (r >= 64) v = q2_w[(r - 64) * 64 + (c - 192)]; }
    else              { if (r < 64)  v = kv2_w[r * 128 + (c - 256)]; }
    W[idx] = v;
}

// ---------------- bias transposes ----------------
// bias1T[h][n][q] = rpb1[rpi[q*576+n]*4+h]
__global__ void bias1_kernel(const float* __restrict__ rpb1, const int* __restrict__ rpi,
                             float* __restrict__ biasT)
{
    int idx = blockIdx.x * 256 + threadIdx.x;
    if (idx >= H2K * NKV1 * NQ1) return;
    int q = idx & 255;
    int n = (idx >> 8) % NKV1;
    int h = idx / (NKV1 * NQ1);
    biasT[idx] = rpb1[rpi[q * NKV1 + n] * H2K + h];
}

// bias2T[h][k][q] = rpb2[rpi[k*576+q]*4+h]
__global__ void bias2_kernel(const float* __restrict__ rpb2, const int* __restrict__ rpi,
                             float* __restrict__ biasT)
{
    int idx = blockIdx.x * 256 + threadIdx.x;
    if (idx >= H2K * NQ1 * NKV1) return;
    int q = idx % NKV1;
    int k = (idx / NKV1) % NQ1;
    int h = idx / (NKV1 * NQ1);
    biasT[idx] = rpb2[rpi[k * NKV1 + q] * H2K + h];
}

// ---------------- attn1: 256 window queries x 576 patch keys, per (win, head) ----------------
// qkvA[tok][192]: 0:64 q1, 64:128 K1, 128:192 V1. No LDS, no barriers.
__launch_bounds__(256)
__global__ void attn1_kernel(const float* __restrict__ qkvA,
                             const float* __restrict__ lnx,
                             const float* __restrict__ biasT,
                             float* __restrict__ xcat)
{
    const int win = blockIdx.x, h = blockIdx.y;
    const int wi = win / NWIN, wj = win % NWIN;
    const int q = threadIdx.x;
    const int pix = (wi * WSZ + (q >> 4)) * WW + wj * WSZ + (q & 15);

    float qv[16];
    {
        const float4* qp = (const float4*)(qkvA + (size_t)pix * 192 + h * HD);
        float4 a = qp[0], b = qp[1], c = qp[2], d = qp[3];
        qv[0]=a.x; qv[1]=a.y; qv[2]=a.z; qv[3]=a.w;
        qv[4]=b.x; qv[5]=b.y; qv[6]=b.z; qv[7]=b.w;
        qv[8]=c.x; qv[9]=c.y; qv[10]=c.z; qv[11]=c.w;
        qv[12]=d.x; qv[13]=d.y; qv[14]=d.z; qv[15]=d.w;
#pragma unroll
        for (int d2 = 0; d2 < 16; d2++) qv[d2] *= SCALE_F;
    }

    const float* bp = biasT + ((size_t)h * NKV1) * NQ1 + q;
    float m = -1e30f, l = 0.f, acc[16];
#pragma unroll
    for (int d = 0; d < 16; d++) acc[d] = 0.f;

    for (int n0 = 0; n0 < NKV1; n0 += 4) {
        float s[4];
        int gp[4]; bool ib[4];
#pragma unroll
        for (int j = 0; j < 4; j++) {
            int n = n0 + j;
            s[j] = bp[(size_t)n * NQ1];
            int rr = wi * WSZ - PADK + n / OWSZ;
            int cc = wj * WSZ - PADK + n % OWSZ;
            ib[j] = (rr >= 0 && rr < HH && cc >= 0 && cc < WW);
            gp[j] = ib[j] ? rr * WW + cc : 0;
        }
#pragma unroll
        for (int j = 0; j < 4; j++)
            if (ib[j]) s[j] += dot16(qv, qkvA + (size_t)gp[j] * 192 + 64 + h * HD);
        float cm = fmaxf(fmaxf(s[0], s[1]), fmaxf(s[2], s[3]));
        float mn = fmaxf(m, cm);
        float corr = __expf(m - mn);
        m = mn; l *= corr;
#pragma unroll
        for (int d = 0; d < 16; d++) acc[d] *= corr;
#pragma unroll
        for (int j = 0; j < 4; j++) {
            float e = __expf(s[j] - mn);
            l += e;
            if (ib[j]) axpy16(acc, e, qkvA + (size_t)gp[j] * 192 + 128 + h * HD);
        }
    }

    float rl = 1.f / l;
    float* op = xcat + (size_t)pix * 128 + h * HD;
    const float* resp = lnx + (size_t)pix * 128 + h * HD;
#pragma unroll
    for (int d = 0; d < 16; d++) op[d] = acc[d] * rl + resp[d];
}

// ---------------- attn2: 576 patch queries x 256 window keys, per (win, head, qsplit) ----------------
// qkvB[tok][192]: 0:64 q2, 64:128 K2, 128:192 V2.
__launch_bounds__(192)
__global__ void attn2_kernel(const float* __restrict__ qkvB,
                             const float* __restrict__ lnx,
                             const float* __restrict__ biasT,
                             float* __restrict__ bb)
{
    const int win = blockIdx.x, h = blockIdx.y;
    const int wi = win / NWIN, wj = win % NWIN;
    const int q = blockIdx.z * 192 + threadIdx.x;   // 0..575
    const int pr = q / OWSZ, pc = q % OWSZ;
    const int gr = wi * WSZ - PADK + pr, gc = wj * WSZ - PADK + pc;
    const bool inb = (gr >= 0 && gr < HH && gc >= 0 && gc < WW);
    const int gpix = inb ? gr * WW + gc : 0;

    float qv[16];
#pragma unroll
    for (int d = 0; d < 16; d++) qv[d] = 0.f;
    if (inb) {
        const float4* qp = (const float4*)(qkvB + (size_t)gpix * 192 + h * HD);
        float4 a = qp[0], b = qp[1], c = qp[2], d = qp[3];
        qv[0]=a.x; qv[1]=a.y; qv[2]=a.z; qv[3]=a.w;
        qv[4]=b.x; qv[5]=b.y; qv[6]=b.z; qv[7]=b.w;
        qv[8]=c.x; qv[9]=c.y; qv[10]=c.z; qv[11]=c.w;
        qv[12]=d.x; qv[13]=d.y; qv[14]=d.z; qv[15]=d.w;
    }
#pragma unroll
    for (int d = 0; d < 16; d++) qv[d] *= SCALE_F;

    const float* bp = biasT + ((size_t)h * NQ1) * NKV1 + q;
    const int wpix0 = (wi * WSZ) * WW + wj * WSZ;
    float m = -1e30f, l = 0.f, acc[16];
#pragma unroll
    for (int d = 0; d < 16; d++) acc[d] = 0.f;

    for (int k0 = 0; k0 < NQ1; k0 += 4) {
        float s[4];
        int kp[4];
#pragma unroll
        for (int j = 0; j < 4; j++) {
            int k = k0 + j;
            s[j] = bp[(size_t)k * NKV1];
            kp[j] = wpix0 + (k >> 4) * WW + (k & 15);
        }
#pragma unroll
        for (int j = 0; j < 4; j++)
            s[j] += dot16(qv, qkvB + (size_t)kp[j] * 192 + 64 + h * HD);
        float cm = fmaxf(fmaxf(s[0], s[1]), fmaxf(s[2], s[3]));
        float mn = fmaxf(m, cm);
        float corr = __expf(m - mn);
        m = mn; l *= corr;
#pragma unroll
        for (int d = 0; d < 16; d++) acc[d] *= corr;
#pragma unroll
        for (int j = 0; j < 4; j++) {
            float e = __expf(s[j] - mn);
            l += e;
            axpy16(acc, e, qkvB + (size_t)kp[j] * 192 + 128 + h * HD);
        }
    }

    float rl = 1.f / l;
    float* op = bb + ((size_t)win * NKV1 + q) * C2K + h * HD;
    const float* resp = lnx + (size_t)gpix * 128 + C2K + h * HD;
#pragma unroll
    for (int d = 0; d < 16; d++) op[d] = acc[d] * rl + (inb ? resp[d] : 0.f);
}

// ---------------- fold (gather form, no atomics) ----------------
__global__ void fold_kernel(const float* __restrict__ bb, float* __restrict__ folded)
{
    int idx = blockIdx.x * 256 + threadIdx.x;
    if (idx >= 200 * 200 * 64) return;
    int c = idx & 63;
    int j = (idx >> 6) % 200;
    int i = idx / (64 * 200);
    int ilo = (i > 23) ? ((i - 8) >> 4) : 0;
    int ihi = min(11, i >> 4);
    int jlo = (j > 23) ? ((j - 8) >> 4) : 0;
    int jhi = min(11, j >> 4);
    float s = 0.f;
    for (int wi = ilo; wi <= ihi; wi++)
        for (int wj = jlo; wj <= jhi; wj++) {
            int p = (i - wi * 16) * OWSZ + (j - wj * 16);
            s += bb[((size_t)(wi * NWIN + wj) * NKV1 + p) * C2K + c];
        }
    folded[idx] = s;
}

// ---------------- bicubic resize 200->192 ----------------
__device__ __forceinline__ float cubicw(float x)
{
    float ax = fabsf(x);
    const float A = -0.75f;
    if (ax <= 1.f) return ((A + 2.f) * ax - (A + 3.f)) * ax * ax + 1.f;
    if (ax < 2.f)  return A * (ax * (ax * (ax - 5.f) + 8.f) - 4.f);
    return 0.f;
}

__global__ void resize_kernel(const float* __restrict__ folded, float* __restrict__ xcat)
{
    int idx = blockIdx.x * 256 + threadIdx.x;
    if (idx >= HH * WW * C2K) return;
    int c = idx & 63;
    int p = (idx >> 6) % WW;
    int o = idx / (C2K * WW);
    const float ratio = 200.f / 192.f;
    float sr = (o + 0.5f) * ratio - 0.5f;
    float sc = (p + 0.5f) * ratio - 0.5f;
    int fr = (int)floorf(sr), fcc = (int)floorf(sc);
    float wc[4]; int ic[4];
#pragma unroll
    for (int u = 0; u < 4; u++) {
        int jj = fcc - 1 + u;
        wc[u] = cubicw(sc - (float)jj);
        ic[u] = min(max(jj, 0), 199);
    }
    float acc = 0.f;
#pragma unroll
    for (int t = 0; t < 4; t++) {
        int ii = fr - 1 + t;
        float wr = cubicw(sr - (float)ii);
        int ir = min(max(ii, 0), 199);
        const float* rowp = folded + ((size_t)ir * 200) * 64 + c;
        float rs = 0.f;
#pragma unroll
        for (int u = 0; u < 4; u++) rs += wc[u] * rowp[(size_t)ic[u] * 64];
        acc += wr * rs;
    }
    xcat[(size_t)(o * WW + p) * 128 + C2K + c] = acc;
}

// ---------------- GEMM: C = (A1 [*A2]) @ B + [bias] [+ R], K = 128 ----------------
// 64(M) x 64(N) tile, 4x4 micro-tile per thread, f32 LDS, swizzled A.
__launch_bounds__(256)
__global__ void gemm_kernel(const float* __restrict__ A1, int a1s,
                            const float* __restrict__ A2, int a2s,
                            const float* __restrict__ B, int ldb, int N,
                            const float* __restrict__ bias,
                            const float* __restrict__ R, int rs,
                            float* __restrict__ C, int cs)
{
    __shared__ float As[64][128];   // As[r][k ^ ((r&3)<<2)]
    __shared__ float Bs[128][64];
    int row0 = blockIdx.x * 64;
    int tid = threadIdx.x;
    int tc = tid & 15, tr = tid >> 4;

    for (int i = tid; i < 64 * 128; i += 256) {
        int r = i >> 7, k = i & 127;
        float v = A1[(size_t)(row0 + r) * a1s + k];
        if (A2) v *= A2[(size_t)(row0 + r) * a2s + k];
        As[r][k ^ ((r & 3) << 2)] = v;
    }

    for (int n0 = 0; n0 < N; n0 += 64) {
        __syncthreads();
        for (int i = tid; i < 128 * 64; i += 256) {
            int k = i >> 6, nn = i & 63;
            Bs[k][nn] = B[(size_t)k * ldb + n0 + nn];
        }
        __syncthreads();
        float creg[4][4];
#pragma unroll
        for (int i = 0; i < 4; i++)
#pragma unroll
            for (int j = 0; j < 4; j++) creg[i][j] = 0.f;
        for (int k = 0; k < 128; k++) {
            float4 b4 = *(const float4*)&Bs[k][tc * 4];
            float a0 = As[tr * 4 + 0][k ^ 0];
            float a1 = As[tr * 4 + 1][k ^ 4];
            float a2 = As[tr * 4 + 2][k ^ 8];
            float a3 = As[tr * 4 + 3][k ^ 12];
            creg[0][0] += a0 * b4.x; creg[0][1] += a0 * b4.y; creg[0][2] += a0 * b4.z; creg[0][3] += a0 * b4.w;
            creg[1][0] += a1 * b4.x; creg[1][1] += a1 * b4.y; creg[1][2] += a1 * b4.z; creg[1][3] += a1 * b4.w;
            creg[2][0] += a2 * b4.x; creg[2][1] += a2 * b4.y; creg[2][2] += a2 * b4.z; creg[2][3] += a2 * b4.w;
            creg[3][0] += a3 * b4.x; creg[3][1] += a3 * b4.y; creg[3][2] += a3 * b4.z; creg[3][3] += a3 * b4.w;
        }
#pragma unroll
        for (int i = 0; i < 4; i++) {
            size_t orow = (size_t)(row0 + tr * 4 + i);
            int col = n0 + tc * 4;
#pragma unroll
            for (int j = 0; j < 4; j++) {
                float acc = creg[i][j];
                if (bias) acc += bias[col + j];
                if (R) acc += R[orow * rs + col + j];
                C[orow * cs + col + j] = acc;
            }
        }
    }
}

// ---------------- depthwise 3x3 conv ----------------
__global__ void dwconv_kernel(const float* __restrict__ x2n,  // h1 + 128, stride 256
                              const float* __restrict__ conv_w,
                              const float* __restrict__ conv_b,
                              float* __restrict__ x2c)
{
    int idx = blockIdx.x * 256 + threadIdx.x;
    if (idx >= NTOK * 128) return;
    int ch = idx & 127, t = idx >> 7;
    int i = t / WW, j = t % WW;
    float acc = conv_b[ch];
#pragma unroll
    for (int a = 0; a < 3; a++) {
        int ii = i + a - 1;
        if (ii < 0 || ii >= HH) continue;
#pragma unroll
        for (int b = 0; b < 3; b++) {
            int jj = j + b - 1;
            if (jj < 0 || jj >= WW) continue;
            acc += conv_w[ch * 9 + a * 3 + b] * x2n[(size_t)(ii * WW + jj) * 256 + ch];
        }
    }
    x2c[(size_t)t * 128 + ch] = acc;
}

extern "C" void kernel_launch(void* const* d_in, const int* in_sizes, int n_in,
                              void* d_out, int out_size, void* d_ws, size_t ws_size,
                              hipStream_t stream)
{
    (void)in_sizes; (void)n_in; (void)out_size; (void)ws_size;
    const float* x_tkn  = (const float*)d_in[0];
    const float* ln1_w  = (const float*)d_in[1];
    const float* ln1_b  = (const float*)d_in[2];
    const float* q1_w   = (const float*)d_in[3];
    const float* kv1_w  = (const float*)d_in[4];
    const float* rpb1   = (const float*)d_in[5];
    const float* q2_w   = (const float*)d_in[6];
    const float* kv2_w  = (const float*)d_in[7];
    const float* rpb2   = (const float*)d_in[8];
    const float* proj_w = (const float*)d_in[9];
    const float* proj_b = (const float*)d_in[10];
    const float* ln2_w  = (const float*)d_in[11];
    const float* ln2_b  = (const float*)d_in[12];
    const float* fc1_w  = (const float*)d_in[13];
    const float* fc1_b  = (const float*)d_in[14];
    const float* sgn_w  = (const float*)d_in[15];
    const float* sgn_b  = (const float*)d_in[16];
    const float* conv_w = (const float*)d_in[17];
    const float* conv_b = (const float*)d_in[18];
    const float* fc2_w  = (const float*)d_in[19];
    const float* fc2_b  = (const float*)d_in[20];
    const int*   rpi    = (const int*)d_in[21];

    float* ws = (float*)d_ws;
    // layout (floats):
    float* lnx    = ws;                 //  0          : 4,718,592  (ln_x; later x_buf)
    float* xcat   = ws + 4718592;       //  4,718,592  : 4,718,592  (x_cat; later x2c)
    float* bbuf   = ws + 9437184;       //  9,437,184  : 5,308,416  (bb; later y)
    float* bias1T = ws + 14745600;      // 14,745,600  : 2,359,296
    float* bias2T = ws + 17104896;      // 17,104,896  :   589,824
    float* wcomb  = ws + 17694720;      // 17,694,720  :    49,152
    float* qkv    = ws + 17743872;      // 17,743,872  : 7,077,888  (qkvA then qkvB)
    float* foldp  = ws + 17743872;      // aliases qkv (qkv dead after attn2)
    float* h1     = ws + 14745600;      // aliases bias/wcomb/qkv (all dead by fc1)
    float* out    = (float*)d_out;

    // 1. LN1
    ln_kernel<<<NTOK / 4, 256, 0, stream>>>(x_tkn, 128, 0, lnx, 128, 0, ln1_w, ln1_b, NTOK);
    // 2. combined weight + bias transposes
    wcomb_kernel<<<(128 * 384 + 255) / 256, 256, 0, stream>>>(q1_w, kv1_w, q2_w, kv2_w, wcomb);
    bias1_kernel<<<(H2K * NKV1 * NQ1) / 256, 256, 0, stream>>>(rpb1, rpi, bias1T);
    bias2_kernel<<<(H2K * NQ1 * NKV1) / 256, 256, 0, stream>>>(rpb2, rpi, bias2T);
    // 3. qkvA = lnx @ Wcomb[:, 0:192]   (q1 | K1 | V1)
    gemm_kernel<<<NTOK / 64, 256, 0, stream>>>(lnx, 128, nullptr, 0, wcomb, 384, 192,
                                               nullptr, nullptr, 0, qkv, 192);
    // 4. attn1 -> xcat[:, 0:64] (+xa residual)
    attn1_kernel<<<dim3(144, 4), 256, 0, stream>>>(qkv, lnx, bias1T, xcat);
    // 5. qkvB = lnx @ Wcomb[:, 192:384]  (q2 | K2 | V2)
    gemm_kernel<<<NTOK / 64, 256, 0, stream>>>(lnx, 128, nullptr, 0, wcomb + 192, 384, 192,
                                               nullptr, nullptr, 0, qkv, 192);
    // 6. attn2 -> bb (+xb_p residual)
    attn2_kernel<<<dim3(144, 4, 3), 192, 0, stream>>>(qkv, lnx, bias2T, bbuf);
    // 7. fold bb -> folded (200x200x64)   (foldp aliases qkv, now dead)
    fold_kernel<<<(200 * 200 * 64) / 256, 256, 0, stream>>>(bbuf, foldp);
    // 8. bicubic resize -> xcat[:, 64:128]
    resize_kernel<<<(HH * WW * C2K) / 256, 256, 0, stream>>>(foldp, xcat);
    // 9. proj: x_buf = xcat @ proj_w + proj_b + x_tkn   (x_buf aliases lnx)
    gemm_kernel<<<NTOK / 64, 256, 0, stream>>>(xcat, 128, nullptr, 0, proj_w, 128, 128, proj_b,
                                               x_tkn, 128, lnx, 128);
    // 10. LN2: y = LN(x_buf)   (y aliases bbuf)
    ln_kernel<<<NTOK / 4, 256, 0, stream>>>(lnx, 128, 0, bbuf, 128, 0, ln2_w, ln2_b, NTOK);
    // 11. fc1: h1 = y @ fc1_w + fc1_b  (N=256)
    gemm_kernel<<<NTOK / 64, 256, 0, stream>>>(bbuf, 128, nullptr, 0, fc1_w, 256, 256, fc1_b,
                                               nullptr, 0, h1, 256);
    // 12. sgn LN on x2 half of h1 (in place)
    ln_kernel<<<NTOK / 4, 256, 0, stream>>>(h1, 256, 128, h1, 256, 128, sgn_w, sgn_b, NTOK);
    // 13. depthwise conv: x2c = dwconv(x2n)   (x2c aliases xcat)
    dwconv_kernel<<<(NTOK * 128) / 256, 256, 0, stream>>>(h1 + 128, conv_w, conv_b, xcat);
    // 14. fc2: out = (x1 * x2c) @ fc2_w + fc2_b + x_buf
    gemm_kernel<<<NTOK / 64, 256, 0, stream>>>(h1, 256, xcat, 128, fc2_w, 128, 128, fc2_b,
                                               lnx, 128, out, 128);
}

// Round 5
// 615.998 us; speedup vs baseline: 1.9335x; 1.9335x over previous
//
#include <hip/hip_runtime.h>
#include <hip/hip_bf16.h>

#define HH 192
#define WW 192
#define NWIN 12
#define WSZ 16
#define OWSZ 24
#define PADK 4
#define NQ1 256      // WS*WS
#define NKV1 576     // OWS*OWS
#define C2K 64
#define H2K 4
#define HD 16        // head dim
#define NTOK (HH*WW)
#define LOG2E 1.4426950408889634f
#define QSCALE (0.25f * LOG2E)

typedef __hip_bfloat16 bf16;
typedef __attribute__((ext_vector_type(8))) short bf16x8;
typedef __attribute__((ext_vector_type(4))) float f32x4;

union B8 { short s[8]; bf16x8 v; unsigned u[4]; };

__device__ __forceinline__ unsigned short f2bfbits(float f)
{
    unsigned u = __float_as_uint(f);
    return (unsigned short)((u + 0x7FFFu + ((u >> 16) & 1u)) >> 16);
}
__device__ __forceinline__ unsigned pack2bf(float a, float b)
{
    return (unsigned)f2bfbits(a) | ((unsigned)f2bfbits(b) << 16);
}

// ---------------- LayerNorm: one wave per 128-ch row ----------------
__launch_bounds__(256)
__global__ void ln_kernel(const float* __restrict__ in, int is, int io,
                          float* __restrict__ out, int os, int oo,
                          const float* __restrict__ g, const float* __restrict__ b,
                          int M)
{
    int row = blockIdx.x * 4 + (threadIdx.x >> 6);
    if (row >= M) return;
    int lane = threadIdx.x & 63;
    const float* p = in + (size_t)row * is + io;
    float v0 = p[lane * 2], v1 = p[lane * 2 + 1];
    float s = v0 + v1, sq = v0 * v0 + v1 * v1;
#pragma unroll
    for (int o = 32; o > 0; o >>= 1) { s += __shfl_xor(s, o); sq += __shfl_xor(sq, o); }
    float mu  = s * 0.0078125f;
    float var = sq * 0.0078125f - mu * mu;
    float inv = 1.0f / sqrtf(var + 1e-5f);
    float* q = out + (size_t)row * os + oo;
    q[lane * 2]     = (v0 - mu) * inv * g[lane * 2]     + b[lane * 2];
    q[lane * 2 + 1] = (v1 - mu) * inv * g[lane * 2 + 1] + b[lane * 2 + 1];
}

// ---------------- combined projection weight ----------------
__global__ void wcomb_kernel(const float* __restrict__ q1_w, const float* __restrict__ kv1_w,
                             const float* __restrict__ q2_w, const float* __restrict__ kv2_w,
                             float* __restrict__ W)
{
    int idx = blockIdx.x * 256 + threadIdx.x;
    if (idx >= 128 * 384) return;
    int r = idx / 384, c = idx % 384;
    float v = 0.f;
    if (c < 64)       { if (r < 64)  v = q1_w[r * 64 + c]; }
    else if (c < 192) { if (r >= 64) v = kv1_w[(r - 64) * 128 + (c - 64)]; }
    else if (c < 256) { if (r >= 64) v = q2_w[(r - 64) * 64 + (c - 192)]; }
    else              { if (r < 64)  v = kv2_w[r * 128 + (c - 256)]; }
    W[idx] = v;
}

// ---------------- bias transposes (pre-scaled by log2(e) for exp2) ----------------
// bias1T[h][n][q] = rpb1[rpi[q*576+n]*4+h] * LOG2E
__global__ void bias1_kernel(const float* __restrict__ rpb1, const int* __restrict__ rpi,
                             float* __restrict__ biasT)
{
    int idx = blockIdx.x * 256 + threadIdx.x;
    if (idx >= H2K * NKV1 * NQ1) return;
    int q = idx & 255;
    int n = (idx >> 8) % NKV1;
    int h = idx / (NKV1 * NQ1);
    biasT[idx] = rpb1[rpi[q * NKV1 + n] * H2K + h] * LOG2E;
}

// bias2T[h][k][q] = rpb2[rpi[k*576+q]*4+h] * LOG2E
__global__ void bias2_kernel(const float* __restrict__ rpb2, const int* __restrict__ rpi,
                             float* __restrict__ biasT)
{
    int idx = blockIdx.x * 256 + threadIdx.x;
    if (idx >= H2K * NQ1 * NKV1) return;
    int q = idx % NKV1;
    int k = (idx / NKV1) % NQ1;
    int h = idx / (NKV1 * NQ1);
    biasT[idx] = rpb2[rpi[k * NKV1 + q] * H2K + h] * LOG2E;
}

// ---------------- attn1 (MFMA): 256 window q x 576 patch keys, per (win, head) ----------------
// qkvA[tok][192]: 0:64 q1 (h*16+d), 64:128 K1, 128:192 V1.
__launch_bounds__(256)
__global__ void attn1_mfma(const float* __restrict__ qkvA,
                           const float* __restrict__ lnx,
                           const float* __restrict__ biasT,
                           float* __restrict__ xcat)
{
    __shared__ unsigned K_lds[NKV1][12];   // rows padded to 12 uints (24 bf16)
    __shared__ unsigned V_lds[NKV1][12];

    const int win = blockIdx.x, h = blockIdx.y;
    const int wi = win / NWIN, wj = win % NWIN;
    const int tid = threadIdx.x;
    const int lane = tid & 63, w = tid >> 6;
    const int g = lane >> 4, qloc = lane & 15;

    // ---- stage K,V (bf16) ----
    for (int n = tid; n < NKV1; n += 256) {
        int rr = wi * WSZ - PADK + n / OWSZ, cc = wj * WSZ - PADK + n % OWSZ;
        bool ib = (rr >= 0 && rr < HH && cc >= 0 && cc < WW);
        unsigned kw[8], vw[8];
        if (ib) {
            const float* kp = qkvA + (size_t)(rr * WW + cc) * 192 + 64 + h * HD;
#pragma unroll
            for (int u = 0; u < 8; u++) {
                kw[u] = pack2bf(kp[2 * u], kp[2 * u + 1]);
                vw[u] = pack2bf(kp[64 + 2 * u], kp[64 + 2 * u + 1]);
            }
        } else {
#pragma unroll
            for (int u = 0; u < 8; u++) { kw[u] = 0; vw[u] = 0; }
        }
        *(uint4*)&K_lds[n][0] = make_uint4(kw[0], kw[1], kw[2], kw[3]);
        *(uint4*)&K_lds[n][4] = make_uint4(kw[4], kw[5], kw[6], kw[7]);
        *(uint4*)&V_lds[n][0] = make_uint4(vw[0], vw[1], vw[2], vw[3]);
        *(uint4*)&V_lds[n][4] = make_uint4(vw[4], vw[5], vw[6], vw[7]);
    }
    __syncthreads();

    // ---- per-wave Q fragments (4 q-tiles of 16 rows) ----
    const int q0base = w * 64;
    bf16x8 qfrag[4];
#pragma unroll
    for (int qt = 0; qt < 4; qt++) {
        int q = q0base + qt * 16 + qloc;
        int pix = (wi * WSZ + (q >> 4)) * WW + wj * WSZ + (q & 15);
        B8 f;
#pragma unroll
        for (int j = 0; j < 8; j++) f.s[j] = 0;
        if (g < 2) {
            const float* qp = qkvA + (size_t)pix * 192 + h * HD + 8 * g;
#pragma unroll
            for (int j = 0; j < 8; j++) f.s[j] = f2bfbits(qp[j] * QSCALE);
        }
        qfrag[qt] = f.v;
    }

    f32x4 O[4];
    float lsum[4];
#pragma unroll
    for (int qt = 0; qt < 4; qt++) { O[qt] = (f32x4){0.f, 0.f, 0.f, 0.f}; lsum[qt] = 0.f; }
    const f32x4 zz = {0.f, 0.f, 0.f, 0.f};

    for (int step = 0; step < 18; step++) {
        const int k0 = step * 32;
        // K A-frags for key-tiles (k0..k0+15) and (k0+16..k0+31)
        bf16x8 kfA, kfB;
        if (g < 2) {
            kfA = *(const bf16x8*)&K_lds[k0 + qloc][4 * g];
            kfB = *(const bf16x8*)&K_lds[k0 + 16 + qloc][4 * g];
        } else {
            B8 zf;
#pragma unroll
            for (int j = 0; j < 8; j++) zf.s[j] = 0;
            kfA = zf.v; kfB = zf.v;
        }
        // V A-frag with PV k-map: k-slot j -> key k0 + 4g + (j&3) + 16*(j>>2)
        B8 vf;
#pragma unroll
        for (int j = 0; j < 8; j++) {
            int key = k0 + 4 * g + (j & 3) + ((j >> 2) << 4);
            unsigned word = V_lds[key][qloc >> 1];
            vf.s[j] = (short)((qloc & 1) ? (word >> 16) : (word & 0xffff));
        }

#pragma unroll
        for (int qt = 0; qt < 4; qt++) {
            f32x4 sA = __builtin_amdgcn_mfma_f32_16x16x32_bf16(kfA, qfrag[qt], zz, 0, 0, 0);
            f32x4 sB = __builtin_amdgcn_mfma_f32_16x16x32_bf16(kfB, qfrag[qt], zz, 0, 0, 0);
            int qa = q0base + qt * 16 + qloc;
            const float* bpA = biasT + ((size_t)h * NKV1 + k0 + 4 * g) * NQ1 + qa;
            const float* bpB = bpA + 16 * NQ1;
            B8 pf;
            float ls = 0.f;
#pragma unroll
            for (int r = 0; r < 4; r++) {
                float pa = exp2f(sA[r] + bpA[(size_t)r * NQ1]);
                float pb = exp2f(sB[r] + bpB[(size_t)r * NQ1]);
                ls += pa + pb;
                pf.s[r] = f2bfbits(pa);
                pf.s[4 + r] = f2bfbits(pb);
            }
            lsum[qt] += ls;
            O[qt] = __builtin_amdgcn_mfma_f32_16x16x32_bf16(vf.v, pf.v, O[qt], 0, 0, 0);
        }
    }

    // ---- finalize: normalize + residual, write ----
#pragma unroll
    for (int qt = 0; qt < 4; qt++) {
        float lt = lsum[qt];
        lt += __shfl_xor(lt, 16);
        lt += __shfl_xor(lt, 32);
        float rl = 1.f / lt;
        int q = q0base + qt * 16 + qloc;
        int pix = (wi * WSZ + (q >> 4)) * WW + wj * WSZ + (q & 15);
        size_t base = (size_t)pix * 128 + h * HD + 4 * g;
#pragma unroll
        for (int r = 0; r < 4; r++)
            xcat[base + r] = O[qt][r] * rl + lnx[base + r];
    }
}

// ---------------- attn2 (MFMA): 576 patch q x 256 window keys, per (win, head) ----------------
// qkvB[tok][192]: 0:64 q2, 64:128 K2, 128:192 V2.
__launch_bounds__(256)
__global__ void attn2_mfma(const float* __restrict__ qkvB,
                           const float* __restrict__ lnx,
                           const float* __restrict__ biasT,
                           float* __restrict__ bb)
{
    __shared__ unsigned K_lds[NQ1][12];
    __shared__ unsigned V_lds[NQ1][12];

    const int win = blockIdx.x, h = blockIdx.y;
    const int wi = win / NWIN, wj = win % NWIN;
    const int tid = threadIdx.x;
    const int lane = tid & 63, w = tid >> 6;
    const int g = lane >> 4, qloc = lane & 15;

    // ---- stage K,V from the window's 256 tokens ----
    if (tid < NQ1) {
        int n = tid;
        int pix = (wi * WSZ + (n >> 4)) * WW + wj * WSZ + (n & 15);
        const float* kp = qkvB + (size_t)pix * 192 + 64 + h * HD;
        unsigned kw[8], vw[8];
#pragma unroll
        for (int u = 0; u < 8; u++) {
            kw[u] = pack2bf(kp[2 * u], kp[2 * u + 1]);
            vw[u] = pack2bf(kp[64 + 2 * u], kp[64 + 2 * u + 1]);
        }
        *(uint4*)&K_lds[n][0] = make_uint4(kw[0], kw[1], kw[2], kw[3]);
        *(uint4*)&K_lds[n][4] = make_uint4(kw[4], kw[5], kw[6], kw[7]);
        *(uint4*)&V_lds[n][0] = make_uint4(vw[0], vw[1], vw[2], vw[3]);
        *(uint4*)&V_lds[n][4] = make_uint4(vw[4], vw[5], vw[6], vw[7]);
    }
    __syncthreads();

    // ---- per-wave Q fragments (9 q-tiles of 16 patch rows) ----
    const int q0base = w * 144;
    bf16x8 qfrag[9];
    bool qin[9];
    int qpix[9];
#pragma unroll
    for (int qt = 0; qt < 9; qt++) {
        int qa = q0base + qt * 16 + qloc;
        int gr = wi * WSZ - PADK + qa / OWSZ, gc = wj * WSZ - PADK + qa % OWSZ;
        bool ib = (gr >= 0 && gr < HH && gc >= 0 && gc < WW);
        qin[qt] = ib;
        qpix[qt] = ib ? gr * WW + gc : 0;
        B8 f;
#pragma unroll
        for (int j = 0; j < 8; j++) f.s[j] = 0;
        if (ib && g < 2) {
            const float* qp = qkvB + (size_t)qpix[qt] * 192 + h * HD + 8 * g;
#pragma unroll
            for (int j = 0; j < 8; j++) f.s[j] = f2bfbits(qp[j] * QSCALE);
        }
        qfrag[qt] = f.v;
    }

    f32x4 O[9];
    float lsum[9];
#pragma unroll
    for (int qt = 0; qt < 9; qt++) { O[qt] = (f32x4){0.f, 0.f, 0.f, 0.f}; lsum[qt] = 0.f; }
    const f32x4 zz = {0.f, 0.f, 0.f, 0.f};

    for (int step = 0; step < 8; step++) {
        const int k0 = step * 32;
        bf16x8 kfA, kfB;
        if (g < 2) {
            kfA = *(const bf16x8*)&K_lds[k0 + qloc][4 * g];
            kfB = *(const bf16x8*)&K_lds[k0 + 16 + qloc][4 * g];
        } else {
            B8 zf;
#pragma unroll
            for (int j = 0; j < 8; j++) zf.s[j] = 0;
            kfA = zf.v; kfB = zf.v;
        }
        B8 vf;
#pragma unroll
        for (int j = 0; j < 8; j++) {
            int key = k0 + 4 * g + (j & 3) + ((j >> 2) << 4);
            unsigned word = V_lds[key][qloc >> 1];
            vf.s[j] = (short)((qloc & 1) ? (word >> 16) : (word & 0xffff));
        }

#pragma unroll
        for (int qt = 0; qt < 9; qt++) {
            f32x4 sA = __builtin_amdgcn_mfma_f32_16x16x32_bf16(kfA, qfrag[qt], zz, 0, 0, 0);
            f32x4 sB = __builtin_amdgcn_mfma_f32_16x16x32_bf16(kfB, qfrag[qt], zz, 0, 0, 0);
            int qa = q0base + qt * 16 + qloc;
            const float* bpA = biasT + ((size_t)h * NQ1 + k0 + 4 * g) * NKV1 + qa;
            const float* bpB = bpA + 16 * NKV1;
            B8 pf;
            float ls = 0.f;
#pragma unroll
            for (int r = 0; r < 4; r++) {
                float pa = exp2f(sA[r] + bpA[(size_t)r * NKV1]);
                float pb = exp2f(sB[r] + bpB[(size_t)r * NKV1]);
                ls += pa + pb;
                pf.s[r] = f2bfbits(pa);
                pf.s[4 + r] = f2bfbits(pb);
            }
            lsum[qt] += ls;
            O[qt] = __builtin_amdgcn_mfma_f32_16x16x32_bf16(vf.v, pf.v, O[qt], 0, 0, 0);
        }
    }

#pragma unroll
    for (int qt = 0; qt < 9; qt++) {
        float lt = lsum[qt];
        lt += __shfl_xor(lt, 16);
        lt += __shfl_xor(lt, 32);
        float rl = 1.f / lt;
        int qa = q0base + qt * 16 + qloc;
        size_t obase = ((size_t)win * NKV1 + qa) * C2K + h * HD + 4 * g;
        size_t rbase = (size_t)qpix[qt] * 128 + C2K + h * HD + 4 * g;
#pragma unroll
        for (int r = 0; r < 4; r++)
            bb[obase + r] = O[qt][r] * rl + (qin[qt] ? lnx[rbase + r] : 0.f);
    }
}

// ---------------- fold (gather form, no atomics) ----------------
__global__ void fold_kernel(const float* __restrict__ bb, float* __restrict__ folded)
{
    int idx = blockIdx.x * 256 + threadIdx.x;
    if (idx >= 200 * 200 * 64) return;
    int c = idx & 63;
    int j = (idx >> 6) % 200;
    int i = idx / (64 * 200);
    int ilo = (i > 23) ? ((i - 8) >> 4) : 0;
    int ihi = min(11, i >> 4);
    int jlo = (j > 23) ? ((j - 8) >> 4) : 0;
    int jhi = min(11, j >> 4);
    float s = 0.f;
    for (int wi = ilo; wi <= ihi; wi++)
        for (int wj = jlo; wj <= jhi; wj++) {
            int p = (i - wi * 16) * OWSZ + (j - wj * 16);
            s += bb[((size_t)(wi * NWIN + wj) * NKV1 + p) * C2K + c];
        }
    folded[idx] = s;
}

// ---------------- bicubic resize 200->192 ----------------
__device__ __forceinline__ float cubicw(float x)
{
    float ax = fabsf(x);
    const float A = -0.75f;
    if (ax <= 1.f) return ((A + 2.f) * ax - (A + 3.f)) * ax * ax + 1.f;
    if (ax < 2.f)  return A * (ax * (ax * (ax - 5.f) + 8.f) - 4.f);
    return 0.f;
}

__global__ void resize_kernel(const float* __restrict__ folded, float* __restrict__ xcat)
{
    int idx = blockIdx.x * 256 + threadIdx.x;
    if (idx >= HH * WW * C2K) return;
    int c = idx & 63;
    int p = (idx >> 6) % WW;
    int o = idx / (C2K * WW);
    const float ratio = 200.f / 192.f;
    float sr = (o + 0.5f) * ratio - 0.5f;
    float sc = (p + 0.5f) * ratio - 0.5f;
    int fr = (int)floorf(sr), fcc = (int)floorf(sc);
    float wc[4]; int ic[4];
#pragma unroll
    for (int u = 0; u < 4; u++) {
        int jj = fcc - 1 + u;
        wc[u] = cubicw(sc - (float)jj);
        ic[u] = min(max(jj, 0), 199);
    }
    float acc = 0.f;
#pragma unroll
    for (int t = 0; t < 4; t++) {
        int ii = fr - 1 + t;
        float wr = cubicw(sr - (float)ii);
        int ir = min(max(ii, 0), 199);
        const float* rowp = folded + ((size_t)ir * 200) * 64 + c;
        float rs = 0.f;
#pragma unroll
        for (int u = 0; u < 4; u++) rs += wc[u] * rowp[(size_t)ic[u] * 64];
        acc += wr * rs;
    }
    xcat[(size_t)(o * WW + p) * 128 + C2K + c] = acc;
}

// ---------------- GEMM: C = (A1 [*A2]) @ B + [bias] [+ R], K = 128 ----------------
__launch_bounds__(256)
__global__ void gemm_kernel(const float* __restrict__ A1, int a1s,
                            const float* __restrict__ A2, int a2s,
                            const float* __restrict__ B, int ldb, int N,
                            const float* __restrict__ bias,
                            const float* __restrict__ R, int rs,
                            float* __restrict__ C, int cs)
{
    __shared__ float As[64][128];   // As[r][k ^ ((r&3)<<2)]
    __shared__ float Bs[128][64];
    int row0 = blockIdx.x * 64;
    int tid = threadIdx.x;
    int tc = tid & 15, tr = tid >> 4;

    for (int i = tid; i < 64 * 128; i += 256) {
        int r = i >> 7, k = i & 127;
        float v = A1[(size_t)(row0 + r) * a1s + k];
        if (A2) v *= A2[(size_t)(row0 + r) * a2s + k];
        As[r][k ^ ((r & 3) << 2)] = v;
    }

    for (int n0 = 0; n0 < N; n0 += 64) {
        __syncthreads();
        for (int i = tid; i < 128 * 64; i += 256) {
            int k = i >> 6, nn = i & 63;
            Bs[k][nn] = B[(size_t)k * ldb + n0 + nn];
        }
        __syncthreads();
        float creg[4][4];
#pragma unroll
        for (int i = 0; i < 4; i++)
#pragma unroll
            for (int j = 0; j < 4; j++) creg[i][j] = 0.f;
        for (int k = 0; k < 128; k++) {
            float4 b4 = *(const float4*)&Bs[k][tc * 4];
            float a0 = As[tr * 4 + 0][k ^ 0];
            float a1 = As[tr * 4 + 1][k ^ 4];
            float a2 = As[tr * 4 + 2][k ^ 8];
            float a3 = As[tr * 4 + 3][k ^ 12];
            creg[0][0] += a0 * b4.x; creg[0][1] += a0 * b4.y; creg[0][2] += a0 * b4.z; creg[0][3] += a0 * b4.w;
            creg[1][0] += a1 * b4.x; creg[1][1] += a1 * b4.y; creg[1][2] += a1 * b4.z; creg[1][3] += a1 * b4.w;
            creg[2][0] += a2 * b4.x; creg[2][1] += a2 * b4.y; creg[2][2] += a2 * b4.z; creg[2][3] += a2 * b4.w;
            creg[3][0] += a3 * b4.x; creg[3][1] += a3 * b4.y; creg[3][2] += a3 * b4.z; creg[3][3] += a3 * b4.w;
        }
#pragma unroll
        for (int i = 0; i < 4; i++) {
            size_t orow = (size_t)(row0 + tr * 4 + i);
            int col = n0 + tc * 4;
#pragma unroll
            for (int j = 0; j < 4; j++) {
                float acc = creg[i][j];
                if (bias) acc += bias[col + j];
                if (R) acc += R[orow * rs + col + j];
                C[orow * cs + col + j] = acc;
            }
        }
    }
}

// ---------------- depthwise 3x3 conv ----------------
__global__ void dwconv_kernel(const float* __restrict__ x2n,
                              const float* __restrict__ conv_w,
                              const float* __restrict__ conv_b,
                              float* __restrict__ x2c)
{
    int idx = blockIdx.x * 256 + threadIdx.x;
    if (idx >= NTOK * 128) return;
    int ch = idx & 127, t = idx >> 7;
    int i = t / WW, j = t % WW;
    float acc = conv_b[ch];
#pragma unroll
    for (int a = 0; a < 3; a++) {
        int ii = i + a - 1;
        if (ii < 0 || ii >= HH) continue;
#pragma unroll
        for (int b = 0; b < 3; b++) {
            int jj = j + b - 1;
            if (jj < 0 || jj >= WW) continue;
            acc += conv_w[ch * 9 + a * 3 + b] * x2n[(size_t)(ii * WW + jj) * 256 + ch];
        }
    }
    x2c[(size_t)t * 128 + ch] = acc;
}

extern "C" void kernel_launch(void* const* d_in, const int* in_sizes, int n_in,
                              void* d_out, int out_size, void* d_ws, size_t ws_size,
                              hipStream_t stream)
{
    (void)in_sizes; (void)n_in; (void)out_size; (void)ws_size;
    const float* x_tkn  = (const float*)d_in[0];
    const float* ln1_w  = (const float*)d_in[1];
    const float* ln1_b  = (const float*)d_in[2];
    const float* q1_w   = (const float*)d_in[3];
    const float* kv1_w  = (const float*)d_in[4];
    const float* rpb1   = (const float*)d_in[5];
    const float* q2_w   = (const float*)d_in[6];
    const float* kv2_w  = (const float*)d_in[7];
    const float* rpb2   = (const float*)d_in[8];
    const float* proj_w = (const float*)d_in[9];
    const float* proj_b = (const float*)d_in[10];
    const float* ln2_w  = (const float*)d_in[11];
    const float* ln2_b  = (const float*)d_in[12];
    const float* fc1_w  = (const float*)d_in[13];
    const float* fc1_b  = (const float*)d_in[14];
    const float* sgn_w  = (const float*)d_in[15];
    const float* sgn_b  = (const float*)d_in[16];
    const float* conv_w = (const float*)d_in[17];
    const float* conv_b = (const float*)d_in[18];
    const float* fc2_w  = (const float*)d_in[19];
    const float* fc2_b  = (const float*)d_in[20];
    const int*   rpi    = (const int*)d_in[21];

    float* ws = (float*)d_ws;
    float* lnx    = ws;                 //  0          : 4,718,592  (ln_x; later x_buf)
    float* xcat   = ws + 4718592;       //  4,718,592  : 4,718,592  (x_cat; later x2c)
    float* bbuf   = ws + 9437184;       //  9,437,184  : 5,308,416  (bb; later y)
    float* bias1T = ws + 14745600;      // 14,745,600  : 2,359,296
    float* bias2T = ws + 17104896;      // 17,104,896  :   589,824
    float* wcomb  = ws + 17694720;      // 17,694,720  :    49,152
    float* qkv    = ws + 17743872;      // 17,743,872  : 7,077,888  (qkvA then qkvB)
    float* foldp  = ws + 17743872;      // aliases qkv (qkv dead after attn2)
    float* h1     = ws + 14745600;      // aliases bias/wcomb/qkv (all dead by fc1)
    float* out    = (float*)d_out;

    // 1. LN1
    ln_kernel<<<NTOK / 4, 256, 0, stream>>>(x_tkn, 128, 0, lnx, 128, 0, ln1_w, ln1_b, NTOK);
    // 2. combined weight + bias transposes
    wcomb_kernel<<<(128 * 384 + 255) / 256, 256, 0, stream>>>(q1_w, kv1_w, q2_w, kv2_w, wcomb);
    bias1_kernel<<<(H2K * NKV1 * NQ1) / 256, 256, 0, stream>>>(rpb1, rpi, bias1T);
    bias2_kernel<<<(H2K * NQ1 * NKV1) / 256, 256, 0, stream>>>(rpb2, rpi, bias2T);
    // 3. qkvA = lnx @ Wcomb[:, 0:192]   (q1 | K1 | V1)
    gemm_kernel<<<NTOK / 64, 256, 0, stream>>>(lnx, 128, nullptr, 0, wcomb, 384, 192,
                                               nullptr, nullptr, 0, qkv, 192);
    // 4. attn1 -> xcat[:, 0:64] (+xa residual)
    attn1_mfma<<<dim3(144, 4), 256, 0, stream>>>(qkv, lnx, bias1T, xcat);
    // 5. qkvB = lnx @ Wcomb[:, 192:384]  (q2 | K2 | V2)
    gemm_kernel<<<NTOK / 64, 256, 0, stream>>>(lnx, 128, nullptr, 0, wcomb + 192, 384, 192,
                                               nullptr, nullptr, 0, qkv, 192);
    // 6. attn2 -> bb (+xb_p residual)
    attn2_mfma<<<dim3(144, 4), 256, 0, stream>>>(qkv, lnx, bias2T, bbuf);
    // 7. fold bb -> folded (200x200x64)   (foldp aliases qkv, now dead)
    fold_kernel<<<(200 * 200 * 64) / 256, 256, 0, stream>>>(bbuf, foldp);
    // 8. bicubic resize -> xcat[:, 64:128]
    resize_kernel<<<(HH * WW * C2K) / 256, 256, 0, stream>>>(foldp, xcat);
    // 9. proj: x_buf = xcat @ proj_w + proj_b + x_tkn   (x_buf aliases lnx)
    gemm_kernel<<<NTOK / 64, 256, 0, stream>>>(xcat, 128, nullptr, 0, proj_w, 128, 128, proj_b,
                                               x_tkn, 128, lnx, 128);
    // 10. LN2: y = LN(x_buf)   (y aliases bbuf)
    ln_kernel<<<NTOK / 4, 256, 0, stream>>>(lnx, 128, 0, bbuf, 128, 0, ln2_w, ln2_b, NTOK);
    // 11. fc1: h1 = y @ fc1_w + fc1_b  (N=256)
    gemm_kernel<<<NTOK / 64, 256, 0, stream>>>(bbuf, 128, nullptr, 0, fc1_w, 256, 256, fc1_b,
                                               nullptr, 0, h1, 256);
    // 12. sgn LN on x2 half of h1 (in place)
    ln_kernel<<<NTOK / 4, 256, 0, stream>>>(h1, 256, 128, h1, 256, 128, sgn_w, sgn_b, NTOK);
    // 13. depthwise conv: x2c = dwconv(x2n)   (x2c aliases xcat)
    dwconv_kernel<<<(NTOK * 128) / 256, 256, 0, stream>>>(h1 + 128, conv_w, conv_b, xcat);
    // 14. fc2: out = (x1 * x2c) @ fc2_w + fc2_b + x_buf
    gemm_kernel<<<NTOK / 64, 256, 0, stream>>>(h1, 256, xcat, 128, fc2_w, 128, 128, fc2_b,
                                               lnx, 128, out, 128);
}

// Round 6
// 355.125 us; speedup vs baseline: 3.3538x; 1.7346x over previous
//
#include <hip/hip_runtime.h>
#include <hip/hip_bf16.h>

#define HH 192
#define WW 192
#define NWIN 12
#define WSZ 16
#define OWSZ 24
#define PADK 4
#define NQ1 256      // WS*WS
#define NKV1 576     // OWS*OWS
#define C2K 64
#define H2K 4
#define HD 16        // head dim
#define NTOK (HH*WW)
#define LOG2E 1.4426950408889634f
#define QSCALE (0.25f * LOG2E)

typedef __hip_bfloat16 bf16;
typedef __attribute__((ext_vector_type(8))) short bf16x8;
typedef __attribute__((ext_vector_type(4))) float f32x4;

union B8 { short s[8]; bf16x8 v; unsigned u[4]; };

__device__ __forceinline__ unsigned short f2bfbits(float f)
{
    unsigned u = __float_as_uint(f);
    return (unsigned short)((u + 0x7FFFu + ((u >> 16) & 1u)) >> 16);
}
__device__ __forceinline__ unsigned pack2bf(float a, float b)
{
    return (unsigned)f2bfbits(a) | ((unsigned)f2bfbits(b) << 16);
}

// ---------------- LayerNorm: one wave per 128-ch row ----------------
__launch_bounds__(256)
__global__ void ln_kernel(const float* __restrict__ in, int is, int io,
                          float* __restrict__ out, int os, int oo,
                          const float* __restrict__ g, const float* __restrict__ b,
                          int M)
{
    int row = blockIdx.x * 4 + (threadIdx.x >> 6);
    if (row >= M) return;
    int lane = threadIdx.x & 63;
    const float* p = in + (size_t)row * is + io;
    float v0 = p[lane * 2], v1 = p[lane * 2 + 1];
    float s = v0 + v1, sq = v0 * v0 + v1 * v1;
#pragma unroll
    for (int o = 32; o > 0; o >>= 1) { s += __shfl_xor(s, o); sq += __shfl_xor(sq, o); }
    float mu  = s * 0.0078125f;
    float var = sq * 0.0078125f - mu * mu;
    float inv = 1.0f / sqrtf(var + 1e-5f);
    float* q = out + (size_t)row * os + oo;
    q[lane * 2]     = (v0 - mu) * inv * g[lane * 2]     + b[lane * 2];
    q[lane * 2 + 1] = (v1 - mu) * inv * g[lane * 2 + 1] + b[lane * 2 + 1];
}

// ---------------- combined projection weight ----------------
__global__ void wcomb_kernel(const float* __restrict__ q1_w, const float* __restrict__ kv1_w,
                             const float* __restrict__ q2_w, const float* __restrict__ kv2_w,
                             float* __restrict__ W)
{
    int idx = blockIdx.x * 256 + threadIdx.x;
    if (idx >= 128 * 384) return;
    int r = idx / 384, c = idx % 384;
    float v = 0.f;
    if (c < 64)       { if (r < 64)  v = q1_w[r * 64 + c]; }
    else if (c < 192) { if (r >= 64) v = kv1_w[(r - 64) * 128 + (c - 64)]; }
    else if (c < 256) { if (r >= 64) v = q2_w[(r - 64) * 64 + (c - 192)]; }
    else              { if (r < 64)  v = kv2_w[r * 128 + (c - 256)]; }
    W[idx] = v;
}

// ---------------- bias transposes (pre-scaled by log2(e) for exp2) ----------------
__global__ void bias1_kernel(const float* __restrict__ rpb1, const int* __restrict__ rpi,
                             float* __restrict__ biasT)
{
    int idx = blockIdx.x * 256 + threadIdx.x;
    if (idx >= H2K * NKV1 * NQ1) return;
    int q = idx & 255;
    int n = (idx >> 8) % NKV1;
    int h = idx / (NKV1 * NQ1);
    biasT[idx] = rpb1[rpi[q * NKV1 + n] * H2K + h] * LOG2E;
}

__global__ void bias2_kernel(const float* __restrict__ rpb2, const int* __restrict__ rpi,
                             float* __restrict__ biasT)
{
    int idx = blockIdx.x * 256 + threadIdx.x;
    if (idx >= H2K * NQ1 * NKV1) return;
    int q = idx % NKV1;
    int k = (idx / NKV1) % NQ1;
    int h = idx / (NKV1 * NQ1);
    biasT[idx] = rpb2[rpi[k * NKV1 + q] * H2K + h] * LOG2E;
}

// ---------------- attn1 (MFMA): 256 window q x 576 patch keys, per (win, head) ----------------
__launch_bounds__(256)
__global__ void attn1_mfma(const float* __restrict__ qkvA,
                           const float* __restrict__ lnx,
                           const float* __restrict__ biasT,
                           float* __restrict__ xcat)
{
    __shared__ unsigned K_lds[NKV1][12];
    __shared__ unsigned V_lds[NKV1][12];

    const int win = blockIdx.x, h = blockIdx.y;
    const int wi = win / NWIN, wj = win % NWIN;
    const int tid = threadIdx.x;
    const int lane = tid & 63, w = tid >> 6;
    const int g = lane >> 4, qloc = lane & 15;

    for (int n = tid; n < NKV1; n += 256) {
        int rr = wi * WSZ - PADK + n / OWSZ, cc = wj * WSZ - PADK + n % OWSZ;
        bool ib = (rr >= 0 && rr < HH && cc >= 0 && cc < WW);
        unsigned kw[8], vw[8];
        if (ib) {
            const float* kp = qkvA + (size_t)(rr * WW + cc) * 192 + 64 + h * HD;
#pragma unroll
            for (int u = 0; u < 8; u++) {
                kw[u] = pack2bf(kp[2 * u], kp[2 * u + 1]);
                vw[u] = pack2bf(kp[64 + 2 * u], kp[64 + 2 * u + 1]);
            }
        } else {
#pragma unroll
            for (int u = 0; u < 8; u++) { kw[u] = 0; vw[u] = 0; }
        }
        *(uint4*)&K_lds[n][0] = make_uint4(kw[0], kw[1], kw[2], kw[3]);
        *(uint4*)&K_lds[n][4] = make_uint4(kw[4], kw[5], kw[6], kw[7]);
        *(uint4*)&V_lds[n][0] = make_uint4(vw[0], vw[1], vw[2], vw[3]);
        *(uint4*)&V_lds[n][4] = make_uint4(vw[4], vw[5], vw[6], vw[7]);
    }
    __syncthreads();

    const int q0base = w * 64;
    bf16x8 qfrag[4];
#pragma unroll
    for (int qt = 0; qt < 4; qt++) {
        int q = q0base + qt * 16 + qloc;
        int pix = (wi * WSZ + (q >> 4)) * WW + wj * WSZ + (q & 15);
        B8 f;
#pragma unroll
        for (int j = 0; j < 8; j++) f.s[j] = 0;
        if (g < 2) {
            const float* qp = qkvA + (size_t)pix * 192 + h * HD + 8 * g;
#pragma unroll
            for (int j = 0; j < 8; j++) f.s[j] = f2bfbits(qp[j] * QSCALE);
        }
        qfrag[qt] = f.v;
    }

    f32x4 O[4];
    float lsum[4];
#pragma unroll
    for (int qt = 0; qt < 4; qt++) { O[qt] = (f32x4){0.f, 0.f, 0.f, 0.f}; lsum[qt] = 0.f; }
    const f32x4 zz = {0.f, 0.f, 0.f, 0.f};

    for (int step = 0; step < 18; step++) {
        const int k0 = step * 32;
        bf16x8 kfA, kfB;
        if (g < 2) {
            kfA = *(const bf16x8*)&K_lds[k0 + qloc][4 * g];
            kfB = *(const bf16x8*)&K_lds[k0 + 16 + qloc][4 * g];
        } else {
            B8 zf;
#pragma unroll
            for (int j = 0; j < 8; j++) zf.s[j] = 0;
            kfA = zf.v; kfB = zf.v;
        }
        B8 vf;
#pragma unroll
        for (int j = 0; j < 8; j++) {
            int key = k0 + 4 * g + (j & 3) + ((j >> 2) << 4);
            unsigned word = V_lds[key][qloc >> 1];
            vf.s[j] = (short)((qloc & 1) ? (word >> 16) : (word & 0xffff));
        }

#pragma unroll
        for (int qt = 0; qt < 4; qt++) {
            f32x4 sA = __builtin_amdgcn_mfma_f32_16x16x32_bf16(kfA, qfrag[qt], zz, 0, 0, 0);
            f32x4 sB = __builtin_amdgcn_mfma_f32_16x16x32_bf16(kfB, qfrag[qt], zz, 0, 0, 0);
            int qa = q0base + qt * 16 + qloc;
            const float* bpA = biasT + ((size_t)h * NKV1 + k0 + 4 * g) * NQ1 + qa;
            const float* bpB = bpA + 16 * NQ1;
            B8 pf;
            float ls = 0.f;
#pragma unroll
            for (int r = 0; r < 4; r++) {
                float pa = exp2f(sA[r] + bpA[(size_t)r * NQ1]);
                float pb = exp2f(sB[r] + bpB[(size_t)r * NQ1]);
                ls += pa + pb;
                pf.s[r] = f2bfbits(pa);
                pf.s[4 + r] = f2bfbits(pb);
            }
            lsum[qt] += ls;
            O[qt] = __builtin_amdgcn_mfma_f32_16x16x32_bf16(vf.v, pf.v, O[qt], 0, 0, 0);
        }
    }

#pragma unroll
    for (int qt = 0; qt < 4; qt++) {
        float lt = lsum[qt];
        lt += __shfl_xor(lt, 16);
        lt += __shfl_xor(lt, 32);
        float rl = 1.f / lt;
        int q = q0base + qt * 16 + qloc;
        int pix = (wi * WSZ + (q >> 4)) * WW + wj * WSZ + (q & 15);
        size_t base = (size_t)pix * 128 + h * HD + 4 * g;
#pragma unroll
        for (int r = 0; r < 4; r++)
            xcat[base + r] = O[qt][r] * rl + lnx[base + r];
    }
}

// ---------------- attn2 (MFMA): 576 patch q x 256 window keys, per (win, head) ----------------
__launch_bounds__(256)
__global__ void attn2_mfma(const float* __restrict__ qkvB,
                           const float* __restrict__ lnx,
                           const float* __restrict__ biasT,
                           float* __restrict__ bb)
{
    __shared__ unsigned K_lds[NQ1][12];
    __shared__ unsigned V_lds[NQ1][12];

    const int win = blockIdx.x, h = blockIdx.y;
    const int wi = win / NWIN, wj = win % NWIN;
    const int tid = threadIdx.x;
    const int lane = tid & 63, w = tid >> 6;
    const int g = lane >> 4, qloc = lane & 15;

    if (tid < NQ1) {
        int n = tid;
        int pix = (wi * WSZ + (n >> 4)) * WW + wj * WSZ + (n & 15);
        const float* kp = qkvB + (size_t)pix * 192 + 64 + h * HD;
        unsigned kw[8], vw[8];
#pragma unroll
        for (int u = 0; u < 8; u++) {
            kw[u] = pack2bf(kp[2 * u], kp[2 * u + 1]);
            vw[u] = pack2bf(kp[64 + 2 * u], kp[64 + 2 * u + 1]);
        }
        *(uint4*)&K_lds[n][0] = make_uint4(kw[0], kw[1], kw[2], kw[3]);
        *(uint4*)&K_lds[n][4] = make_uint4(kw[4], kw[5], kw[6], kw[7]);
        *(uint4*)&V_lds[n][0] = make_uint4(vw[0], vw[1], vw[2], vw[3]);
        *(uint4*)&V_lds[n][4] = make_uint4(vw[4], vw[5], vw[6], vw[7]);
    }
    __syncthreads();

    const int q0base = w * 144;
    bf16x8 qfrag[9];
    bool qin[9];
    int qpix[9];
#pragma unroll
    for (int qt = 0; qt < 9; qt++) {
        int qa = q0base + qt * 16 + qloc;
        int gr = wi * WSZ - PADK + qa / OWSZ, gc = wj * WSZ - PADK + qa % OWSZ;
        bool ib = (gr >= 0 && gr < HH && gc >= 0 && gc < WW);
        qin[qt] = ib;
        qpix[qt] = ib ? gr * WW + gc : 0;
        B8 f;
#pragma unroll
        for (int j = 0; j < 8; j++) f.s[j] = 0;
        if (ib && g < 2) {
            const float* qp = qkvB + (size_t)qpix[qt] * 192 + h * HD + 8 * g;
#pragma unroll
            for (int j = 0; j < 8; j++) f.s[j] = f2bfbits(qp[j] * QSCALE);
        }
        qfrag[qt] = f.v;
    }

    f32x4 O[9];
    float lsum[9];
#pragma unroll
    for (int qt = 0; qt < 9; qt++) { O[qt] = (f32x4){0.f, 0.f, 0.f, 0.f}; lsum[qt] = 0.f; }
    const f32x4 zz = {0.f, 0.f, 0.f, 0.f};

    for (int step = 0; step < 8; step++) {
        const int k0 = step * 32;
        bf16x8 kfA, kfB;
        if (g < 2) {
            kfA = *(const bf16x8*)&K_lds[k0 + qloc][4 * g];
            kfB = *(const bf16x8*)&K_lds[k0 + 16 + qloc][4 * g];
        } else {
            B8 zf;
#pragma unroll
            for (int j = 0; j < 8; j++) zf.s[j] = 0;
            kfA = zf.v; kfB = zf.v;
        }
        B8 vf;
#pragma unroll
        for (int j = 0; j < 8; j++) {
            int key = k0 + 4 * g + (j & 3) + ((j >> 2) << 4);
            unsigned word = V_lds[key][qloc >> 1];
            vf.s[j] = (short)((qloc & 1) ? (word >> 16) : (word & 0xffff));
        }

#pragma unroll
        for (int qt = 0; qt < 9; qt++) {
            f32x4 sA = __builtin_amdgcn_mfma_f32_16x16x32_bf16(kfA, qfrag[qt], zz, 0, 0, 0);
            f32x4 sB = __builtin_amdgcn_mfma_f32_16x16x32_bf16(kfB, qfrag[qt], zz, 0, 0, 0);
            int qa = q0base + qt * 16 + qloc;
            const float* bpA = biasT + ((size_t)h * NQ1 + k0 + 4 * g) * NKV1 + qa;
            const float* bpB = bpA + 16 * NKV1;
            B8 pf;
            float ls = 0.f;
#pragma unroll
            for (int r = 0; r < 4; r++) {
                float pa = exp2f(sA[r] + bpA[(size_t)r * NKV1]);
                float pb = exp2f(sB[r] + bpB[(size_t)r * NKV1]);
                ls += pa + pb;
                pf.s[r] = f2bfbits(pa);
                pf.s[4 + r] = f2bfbits(pb);
            }
            lsum[qt] += ls;
            O[qt] = __builtin_amdgcn_mfma_f32_16x16x32_bf16(vf.v, pf.v, O[qt], 0, 0, 0);
        }
    }

#pragma unroll
    for (int qt = 0; qt < 9; qt++) {
        float lt = lsum[qt];
        lt += __shfl_xor(lt, 16);
        lt += __shfl_xor(lt, 32);
        float rl = 1.f / lt;
        int qa = q0base + qt * 16 + qloc;
        size_t obase = ((size_t)win * NKV1 + qa) * C2K + h * HD + 4 * g;
        size_t rbase = (size_t)qpix[qt] * 128 + C2K + h * HD + 4 * g;
#pragma unroll
        for (int r = 0; r < 4; r++)
            bb[obase + r] = O[qt][r] * rl + (qin[qt] ? lnx[rbase + r] : 0.f);
    }
}

// ---------------- fold (gather form, no atomics) ----------------
__global__ void fold_kernel(const float* __restrict__ bb, float* __restrict__ folded)
{
    int idx = blockIdx.x * 256 + threadIdx.x;
    if (idx >= 200 * 200 * 64) return;
    int c = idx & 63;
    int j = (idx >> 6) % 200;
    int i = idx / (64 * 200);
    int ilo = (i > 23) ? ((i - 8) >> 4) : 0;
    int ihi = min(11, i >> 4);
    int jlo = (j > 23) ? ((j - 8) >> 4) : 0;
    int jhi = min(11, j >> 4);
    float s = 0.f;
    for (int wi = ilo; wi <= ihi; wi++)
        for (int wj = jlo; wj <= jhi; wj++) {
            int p = (i - wi * 16) * OWSZ + (j - wj * 16);
            s += bb[((size_t)(wi * NWIN + wj) * NKV1 + p) * C2K + c];
        }
    folded[idx] = s;
}

// ---------------- bicubic resize 200->192 ----------------
__device__ __forceinline__ float cubicw(float x)
{
    float ax = fabsf(x);
    const float A = -0.75f;
    if (ax <= 1.f) return ((A + 2.f) * ax - (A + 3.f)) * ax * ax + 1.f;
    if (ax < 2.f)  return A * (ax * (ax * (ax - 5.f) + 8.f) - 4.f);
    return 0.f;
}

__global__ void resize_kernel(const float* __restrict__ folded, float* __restrict__ xcat)
{
    int idx = blockIdx.x * 256 + threadIdx.x;
    if (idx >= HH * WW * C2K) return;
    int c = idx & 63;
    int p = (idx >> 6) % WW;
    int o = idx / (C2K * WW);
    const float ratio = 200.f / 192.f;
    float sr = (o + 0.5f) * ratio - 0.5f;
    float sc = (p + 0.5f) * ratio - 0.5f;
    int fr = (int)floorf(sr), fcc = (int)floorf(sc);
    float wc[4]; int ic[4];
#pragma unroll
    for (int u = 0; u < 4; u++) {
        int jj = fcc - 1 + u;
        wc[u] = cubicw(sc - (float)jj);
        ic[u] = min(max(jj, 0), 199);
    }
    float acc = 0.f;
#pragma unroll
    for (int t = 0; t < 4; t++) {
        int ii = fr - 1 + t;
        float wr = cubicw(sr - (float)ii);
        int ir = min(max(ii, 0), 199);
        const float* rowp = folded + ((size_t)ir * 200) * 64 + c;
        float rs = 0.f;
#pragma unroll
        for (int u = 0; u < 4; u++) rs += wc[u] * rowp[(size_t)ic[u] * 64];
        acc += wr * rs;
    }
    xcat[(size_t)(o * WW + p) * 128 + C2K + c] = acc;
}

// ---------------- MFMA GEMM: C = (A1 [*A2]) @ W + [bias] [+ R], K = 128 ----------------
// Role-swap: A-operand = W^T tiles (kept in registers), B-operand = X^T (streamed).
// Each block: 4 waves x NTPW n-tiles, 4 token-tiles of 16 rows. No LDS.
template<int NTPW>
__launch_bounds__(256)
__global__ void gemm_mfma(const float* __restrict__ A1, int a1s,
                          const float* __restrict__ A2, int a2s,
                          const float* __restrict__ Wm, int ldb,
                          const float* __restrict__ bias,
                          const float* __restrict__ R, int rs,
                          float* __restrict__ C, int cs)
{
    const int tid = threadIdx.x;
    const int lane = tid & 63, w = tid >> 6;
    const int g = lane >> 4, nl = lane & 15;

    // W^T A-frags: frag (t, ks); lane (row=nl within n-tile, g) holds
    // W[ks*32 + 8g + j][n0t + nl], j=0..7  (same k-map as B-frags below)
    bf16x8 wf[NTPW][4];
#pragma unroll
    for (int t = 0; t < NTPW; t++) {
        int ncol = (w * NTPW + t) * 16 + nl;
#pragma unroll
        for (int ks = 0; ks < 4; ks++) {
            const float* wp = Wm + (size_t)(ks * 32 + 8 * g) * ldb + ncol;
            B8 f;
#pragma unroll
            for (int j = 0; j < 8; j++) f.s[j] = f2bfbits(wp[(size_t)j * ldb]);
            wf[t][ks] = f.v;
        }
    }

    const f32x4 zz = {0.f, 0.f, 0.f, 0.f};
    for (int it = 0; it < 4; it++) {
        const int row = (blockIdx.x * 4 + it) * 16 + nl;   // this lane's token row
        // X^T B-frags: lane (col=nl, g) holds X[row][ks*32 + 8g + j]
        bf16x8 xf[4];
        const float* ap = A1 + (size_t)row * a1s + 8 * g;
#pragma unroll
        for (int ks = 0; ks < 4; ks++) {
            float4 v0 = *(const float4*)(ap + ks * 32);
            float4 v1 = *(const float4*)(ap + ks * 32 + 4);
            if (A2) {
                const float* ap2 = A2 + (size_t)row * a2s + 8 * g + ks * 32;
                float4 m0 = *(const float4*)(ap2);
                float4 m1 = *(const float4*)(ap2 + 4);
                v0.x *= m0.x; v0.y *= m0.y; v0.z *= m0.z; v0.w *= m0.w;
                v1.x *= m1.x; v1.y *= m1.y; v1.z *= m1.z; v1.w *= m1.w;
            }
            B8 f;
            f.u[0] = pack2bf(v0.x, v0.y);
            f.u[1] = pack2bf(v0.z, v0.w);
            f.u[2] = pack2bf(v1.x, v1.y);
            f.u[3] = pack2bf(v1.z, v1.w);
            xf[ks] = f.v;
        }

        f32x4 acc[NTPW];
#pragma unroll
        for (int t = 0; t < NTPW; t++) acc[t] = zz;
#pragma unroll
        for (int ks = 0; ks < 4; ks++)
#pragma unroll
            for (int t = 0; t < NTPW; t++)
                acc[t] = __builtin_amdgcn_mfma_f32_16x16x32_bf16(wf[t][ks], xf[ks], acc[t], 0, 0, 0);

#pragma unroll
        for (int t = 0; t < NTPW; t++) {
            const int n0t = (w * NTPW + t) * 16 + 4 * g;
            float4 o;
            o.x = acc[t][0]; o.y = acc[t][1]; o.z = acc[t][2]; o.w = acc[t][3];
            if (bias) {
                float4 bv = *(const float4*)(bias + n0t);
                o.x += bv.x; o.y += bv.y; o.z += bv.z; o.w += bv.w;
            }
            if (R) {
                float4 rv = *(const float4*)(R + (size_t)row * rs + n0t);
                o.x += rv.x; o.y += rv.y; o.z += rv.z; o.w += rv.w;
            }
            *(float4*)(C + (size_t)row * cs + n0t) = o;
        }
    }
}

// ---------------- depthwise 3x3 conv ----------------
__global__ void dwconv_kernel(const float* __restrict__ x2n,
                              const float* __restrict__ conv_w,
                              const float* __restrict__ conv_b,
                              float* __restrict__ x2c)
{
    int idx = blockIdx.x * 256 + threadIdx.x;
    if (idx >= NTOK * 128) return;
    int ch = idx & 127, t = idx >> 7;
    int i = t / WW, j = t % WW;
    float acc = conv_b[ch];
#pragma unroll
    for (int a = 0; a < 3; a++) {
        int ii = i + a - 1;
        if (ii < 0 || ii >= HH) continue;
#pragma unroll
        for (int b = 0; b < 3; b++) {
            int jj = j + b - 1;
            if (jj < 0 || jj >= WW) continue;
            acc += conv_w[ch * 9 + a * 3 + b] * x2n[(size_t)(ii * WW + jj) * 256 + ch];
        }
    }
    x2c[(size_t)t * 128 + ch] = acc;
}

extern "C" void kernel_launch(void* const* d_in, const int* in_sizes, int n_in,
                              void* d_out, int out_size, void* d_ws, size_t ws_size,
                              hipStream_t stream)
{
    (void)in_sizes; (void)n_in; (void)out_size; (void)ws_size;
    const float* x_tkn  = (const float*)d_in[0];
    const float* ln1_w  = (const float*)d_in[1];
    const float* ln1_b  = (const float*)d_in[2];
    const float* q1_w   = (const float*)d_in[3];
    const float* kv1_w  = (const float*)d_in[4];
    const float* rpb1   = (const float*)d_in[5];
    const float* q2_w   = (const float*)d_in[6];
    const float* kv2_w  = (const float*)d_in[7];
    const float* rpb2   = (const float*)d_in[8];
    const float* proj_w = (const float*)d_in[9];
    const float* proj_b = (const float*)d_in[10];
    const float* ln2_w  = (const float*)d_in[11];
    const float* ln2_b  = (const float*)d_in[12];
    const float* fc1_w  = (const float*)d_in[13];
    const float* fc1_b  = (const float*)d_in[14];
    const float* sgn_w  = (const float*)d_in[15];
    const float* sgn_b  = (const float*)d_in[16];
    const float* conv_w = (const float*)d_in[17];
    const float* conv_b = (const float*)d_in[18];
    const float* fc2_w  = (const float*)d_in[19];
    const float* fc2_b  = (const float*)d_in[20];
    const int*   rpi    = (const int*)d_in[21];

    float* ws = (float*)d_ws;
    float* lnx    = ws;                 //  0          : 4,718,592  (ln_x; later x_buf)
    float* xcat   = ws + 4718592;       //  4,718,592  : 4,718,592  (x_cat; later x2c)
    float* bbuf   = ws + 9437184;       //  9,437,184  : 5,308,416  (bb; later y)
    float* bias1T = ws + 14745600;      // 14,745,600  : 2,359,296
    float* bias2T = ws + 17104896;      // 17,104,896  :   589,824
    float* wcomb  = ws + 17694720;      // 17,694,720  :    49,152
    float* qkv    = ws + 17743872;      // 17,743,872  : 7,077,888  (qkvA then qkvB)
    float* foldp  = ws + 17743872;      // aliases qkv (qkv dead after attn2)
    float* h1     = ws + 14745600;      // aliases bias/wcomb/qkv (all dead by fc1)
    float* out    = (float*)d_out;

    // 1. LN1
    ln_kernel<<<NTOK / 4, 256, 0, stream>>>(x_tkn, 128, 0, lnx, 128, 0, ln1_w, ln1_b, NTOK);
    // 2. combined weight + bias transposes
    wcomb_kernel<<<(128 * 384 + 255) / 256, 256, 0, stream>>>(q1_w, kv1_w, q2_w, kv2_w, wcomb);
    bias1_kernel<<<(H2K * NKV1 * NQ1) / 256, 256, 0, stream>>>(rpb1, rpi, bias1T);
    bias2_kernel<<<(H2K * NQ1 * NKV1) / 256, 256, 0, stream>>>(rpb2, rpi, bias2T);
    // 3. qkvA = lnx @ Wcomb[:, 0:192]
    gemm_mfma<3><<<NTOK / 64, 256, 0, stream>>>(lnx, 128, nullptr, 0, wcomb, 384,
                                                nullptr, nullptr, 0, qkv, 192);
    // 4. attn1 -> xcat[:, 0:64] (+xa residual)
    attn1_mfma<<<dim3(144, 4), 256, 0, stream>>>(qkv, lnx, bias1T, xcat);
    // 5. qkvB = lnx @ Wcomb[:, 192:384]
    gemm_mfma<3><<<NTOK / 64, 256, 0, stream>>>(lnx, 128, nullptr, 0, wcomb + 192, 384,
                                                nullptr, nullptr, 0, qkv, 192);
    // 6. attn2 -> bb (+xb_p residual)
    attn2_mfma<<<dim3(144, 4), 256, 0, stream>>>(qkv, lnx, bias2T, bbuf);
    // 7. fold bb -> folded (200x200x64)
    fold_kernel<<<(200 * 200 * 64) / 256, 256, 0, stream>>>(bbuf, foldp);
    // 8. bicubic resize -> xcat[:, 64:128]
    resize_kernel<<<(HH * WW * C2K) / 256, 256, 0, stream>>>(foldp, xcat);
    // 9. proj: x_buf = xcat @ proj_w + proj_b + x_tkn
    gemm_mfma<2><<<NTOK / 64, 256, 0, stream>>>(xcat, 128, nullptr, 0, proj_w, 128,
                                                proj_b, x_tkn, 128, lnx, 128);
    // 10. LN2: y = LN(x_buf)
    ln_kernel<<<NTOK / 4, 256, 0, stream>>>(lnx, 128, 0, bbuf, 128, 0, ln2_w, ln2_b, NTOK);
    // 11. fc1: h1 = y @ fc1_w + fc1_b  (N=256)
    gemm_mfma<4><<<NTOK / 64, 256, 0, stream>>>(bbuf, 128, nullptr, 0, fc1_w, 256,
                                                fc1_b, nullptr, 0, h1, 256);
    // 12. sgn LN on x2 half of h1 (in place)
    ln_kernel<<<NTOK / 4, 256, 0, stream>>>(h1, 256, 128, h1, 256, 128, sgn_w, sgn_b, NTOK);
    // 13. depthwise conv: x2c = dwconv(x2n)
    dwconv_kernel<<<(NTOK * 128) / 256, 256, 0, stream>>>(h1 + 128, conv_w, conv_b, xcat);
    // 14. fc2: out = (x1 * x2c) @ fc2_w + fc2_b + x_buf
    gemm_mfma<2><<<NTOK / 64, 256, 0, stream>>>(h1, 256, xcat, 128, fc2_w, 128,
                                                fc2_b, lnx, 128, out, 128);
}

// Round 7
// 320.333 us; speedup vs baseline: 3.7180x; 1.1086x over previous
//
#include <hip/hip_runtime.h>
#include <hip/hip_bf16.h>

#define HH 192
#define WW 192
#define NWIN 12
#define WSZ 16
#define OWSZ 24
#define PADK 4
#define NQ1 256      // WS*WS
#define NKV1 576     // OWS*OWS
#define C2K 64
#define H2K 4
#define HD 16        // head dim
#define NTOK (HH*WW)
#define LOG2E 1.4426950408889634f
#define QSCALE (0.25f * LOG2E)

typedef __hip_bfloat16 bf16;
typedef __attribute__((ext_vector_type(8))) short bf16x8;
typedef __attribute__((ext_vector_type(4))) float f32x4;

union B8 { short s[8]; bf16x8 v; unsigned u[4]; };

// single-instruction RNE pack of two f32 -> packed bf16x2
__device__ __forceinline__ unsigned cvtpk(float lo, float hi)
{
    unsigned r;
    asm("v_cvt_pk_bf16_f32 %0, %1, %2" : "=v"(r) : "v"(lo), "v"(hi));
    return r;
}

// ---------------- LayerNorm: one wave per 128-ch row ----------------
__launch_bounds__(256)
__global__ void ln_kernel(const float* __restrict__ in, int is, int io,
                          float* __restrict__ out, int os, int oo,
                          const float* __restrict__ g, const float* __restrict__ b,
                          int M)
{
    int row = blockIdx.x * 4 + (threadIdx.x >> 6);
    if (row >= M) return;
    int lane = threadIdx.x & 63;
    const float* p = in + (size_t)row * is + io;
    float v0 = p[lane * 2], v1 = p[lane * 2 + 1];
    float s = v0 + v1, sq = v0 * v0 + v1 * v1;
#pragma unroll
    for (int o = 32; o > 0; o >>= 1) { s += __shfl_xor(s, o); sq += __shfl_xor(sq, o); }
    float mu  = s * 0.0078125f;
    float var = sq * 0.0078125f - mu * mu;
    float inv = 1.0f / sqrtf(var + 1e-5f);
    float* q = out + (size_t)row * os + oo;
    q[lane * 2]     = (v0 - mu) * inv * g[lane * 2]     + b[lane * 2];
    q[lane * 2 + 1] = (v1 - mu) * inv * g[lane * 2 + 1] + b[lane * 2 + 1];
}

// ---------------- combined projection weight ----------------
__global__ void wcomb_kernel(const float* __restrict__ q1_w, const float* __restrict__ kv1_w,
                             const float* __restrict__ q2_w, const float* __restrict__ kv2_w,
                             float* __restrict__ W)
{
    int idx = blockIdx.x * 256 + threadIdx.x;
    if (idx >= 128 * 384) return;
    int r = idx / 384, c = idx % 384;
    float v = 0.f;
    if (c < 64)       { if (r < 64)  v = q1_w[r * 64 + c]; }
    else if (c < 192) { if (r >= 64) v = kv1_w[(r - 64) * 128 + (c - 64)]; }
    else if (c < 256) { if (r >= 64) v = q2_w[(r - 64) * 64 + (c - 192)]; }
    else              { if (r < 64)  v = kv2_w[r * 128 + (c - 256)]; }
    W[idx] = v;
}

// ---------------- bias transposes (pre-scaled by log2(e) for exp2) ----------------
__global__ void bias1_kernel(const float* __restrict__ rpb1, const int* __restrict__ rpi,
                             float* __restrict__ biasT)
{
    int idx = blockIdx.x * 256 + threadIdx.x;
    if (idx >= H2K * NKV1 * NQ1) return;
    int q = idx & 255;
    int n = (idx >> 8) % NKV1;
    int h = idx / (NKV1 * NQ1);
    biasT[idx] = rpb1[rpi[q * NKV1 + n] * H2K + h] * LOG2E;
}

__global__ void bias2_kernel(const float* __restrict__ rpb2, const int* __restrict__ rpi,
                             float* __restrict__ biasT)
{
    int idx = blockIdx.x * 256 + threadIdx.x;
    if (idx >= H2K * NQ1 * NKV1) return;
    int q = idx % NKV1;
    int k = (idx / NKV1) % NQ1;
    int h = idx / (NKV1 * NQ1);
    biasT[idx] = rpb2[rpi[k * NKV1 + q] * H2K + h] * LOG2E;
}

// ---------------- attn1 (MFMA): 256 window q x 576 patch keys ----------------
// grid (144, 4, 2): z splits the 256 queries into 2 chunks of 128 (2 q-tiles/wave).
__launch_bounds__(256)
__global__ void attn1_mfma(const float* __restrict__ qkvA,
                           const float* __restrict__ lnx,
                           const float* __restrict__ biasT,
                           float* __restrict__ xcat)
{
    __shared__ unsigned K_lds[NKV1][12];
    __shared__ unsigned V_lds[NKV1][12];

    const int win = blockIdx.x, h = blockIdx.y;
    const int wi = win / NWIN, wj = win % NWIN;
    const int tid = threadIdx.x;
    const int lane = tid & 63, w = tid >> 6;
    const int g = lane >> 4, qloc = lane & 15;

    for (int n = tid; n < NKV1; n += 256) {
        int rr = wi * WSZ - PADK + n / OWSZ, cc = wj * WSZ - PADK + n % OWSZ;
        bool ib = (rr >= 0 && rr < HH && cc >= 0 && cc < WW);
        unsigned kw[8], vw[8];
        if (ib) {
            const float* kp = qkvA + (size_t)(rr * WW + cc) * 192 + 64 + h * HD;
#pragma unroll
            for (int u = 0; u < 8; u++) {
                kw[u] = cvtpk(kp[2 * u], kp[2 * u + 1]);
                vw[u] = cvtpk(kp[64 + 2 * u], kp[64 + 2 * u + 1]);
            }
        } else {
#pragma unroll
            for (int u = 0; u < 8; u++) { kw[u] = 0; vw[u] = 0; }
        }
        *(uint4*)&K_lds[n][0] = make_uint4(kw[0], kw[1], kw[2], kw[3]);
        *(uint4*)&K_lds[n][4] = make_uint4(kw[4], kw[5], kw[6], kw[7]);
        *(uint4*)&V_lds[n][0] = make_uint4(vw[0], vw[1], vw[2], vw[3]);
        *(uint4*)&V_lds[n][4] = make_uint4(vw[4], vw[5], vw[6], vw[7]);
    }
    __syncthreads();

    const int q0base = blockIdx.z * 128 + w * 32;
    bf16x8 qfrag[2];
#pragma unroll
    for (int qt = 0; qt < 2; qt++) {
        int q = q0base + qt * 16 + qloc;
        int pix = (wi * WSZ + (q >> 4)) * WW + wj * WSZ + (q & 15);
        B8 f;
#pragma unroll
        for (int j = 0; j < 4; j++) f.u[j] = 0;
        if (g < 2) {
            const float* qp = qkvA + (size_t)pix * 192 + h * HD + 8 * g;
#pragma unroll
            for (int j = 0; j < 4; j++)
                f.u[j] = cvtpk(qp[2 * j] * QSCALE, qp[2 * j + 1] * QSCALE);
        }
        qfrag[qt] = f.v;
    }

    f32x4 O[2];
    float lsum[2];
#pragma unroll
    for (int qt = 0; qt < 2; qt++) { O[qt] = (f32x4){0.f, 0.f, 0.f, 0.f}; lsum[qt] = 0.f; }
    const f32x4 zz = {0.f, 0.f, 0.f, 0.f};

    for (int step = 0; step < 18; step++) {
        const int k0 = step * 32;
        bf16x8 kfA, kfB;
        if (g < 2) {
            kfA = *(const bf16x8*)&K_lds[k0 + qloc][4 * g];
            kfB = *(const bf16x8*)&K_lds[k0 + 16 + qloc][4 * g];
        } else {
            B8 zf;
#pragma unroll
            for (int j = 0; j < 4; j++) zf.u[j] = 0;
            kfA = zf.v; kfB = zf.v;
        }
        B8 vf;
#pragma unroll
        for (int j = 0; j < 8; j++) {
            int key = k0 + 4 * g + (j & 3) + ((j >> 2) << 4);
            unsigned word = V_lds[key][qloc >> 1];
            vf.s[j] = (short)((qloc & 1) ? (word >> 16) : (word & 0xffff));
        }

#pragma unroll
        for (int qt = 0; qt < 2; qt++) {
            f32x4 sA = __builtin_amdgcn_mfma_f32_16x16x32_bf16(kfA, qfrag[qt], zz, 0, 0, 0);
            f32x4 sB = __builtin_amdgcn_mfma_f32_16x16x32_bf16(kfB, qfrag[qt], zz, 0, 0, 0);
            int qa = q0base + qt * 16 + qloc;
            const float* bpA = biasT + ((size_t)h * NKV1 + k0 + 4 * g) * NQ1 + qa;
            const float* bpB = bpA + 16 * NQ1;
            float pa[4], pb[4];
            float ls = 0.f;
#pragma unroll
            for (int r = 0; r < 4; r++) {
                pa[r] = exp2f(sA[r] + bpA[(size_t)r * NQ1]);
                pb[r] = exp2f(sB[r] + bpB[(size_t)r * NQ1]);
                ls += pa[r] + pb[r];
            }
            B8 pf;
            pf.u[0] = cvtpk(pa[0], pa[1]);
            pf.u[1] = cvtpk(pa[2], pa[3]);
            pf.u[2] = cvtpk(pb[0], pb[1]);
            pf.u[3] = cvtpk(pb[2], pb[3]);
            lsum[qt] += ls;
            O[qt] = __builtin_amdgcn_mfma_f32_16x16x32_bf16(vf.v, pf.v, O[qt], 0, 0, 0);
        }
    }

#pragma unroll
    for (int qt = 0; qt < 2; qt++) {
        float lt = lsum[qt];
        lt += __shfl_xor(lt, 16);
        lt += __shfl_xor(lt, 32);
        float rl = 1.f / lt;
        int q = q0base + qt * 16 + qloc;
        int pix = (wi * WSZ + (q >> 4)) * WW + wj * WSZ + (q & 15);
        size_t base = (size_t)pix * 128 + h * HD + 4 * g;
#pragma unroll
        for (int r = 0; r < 4; r++)
            xcat[base + r] = O[qt][r] * rl + lnx[base + r];
    }
}

// ---------------- attn2 (MFMA): 576 patch q x 256 window keys ----------------
// grid (144, 4, 3): z splits the 576 queries into 3 chunks of 192 (3 q-tiles/wave).
__launch_bounds__(256)
__global__ void attn2_mfma(const float* __restrict__ qkvB,
                           const float* __restrict__ lnx,
                           const float* __restrict__ biasT,
                           float* __restrict__ bb)
{
    __shared__ unsigned K_lds[NQ1][12];
    __shared__ unsigned V_lds[NQ1][12];

    const int win = blockIdx.x, h = blockIdx.y;
    const int wi = win / NWIN, wj = win % NWIN;
    const int tid = threadIdx.x;
    const int lane = tid & 63, w = tid >> 6;
    const int g = lane >> 4, qloc = lane & 15;

    if (tid < NQ1) {
        int n = tid;
        int pix = (wi * WSZ + (n >> 4)) * WW + wj * WSZ + (n & 15);
        const float* kp = qkvB + (size_t)pix * 192 + 64 + h * HD;
        unsigned kw[8], vw[8];
#pragma unroll
        for (int u = 0; u < 8; u++) {
            kw[u] = cvtpk(kp[2 * u], kp[2 * u + 1]);
            vw[u] = cvtpk(kp[64 + 2 * u], kp[64 + 2 * u + 1]);
        }
        *(uint4*)&K_lds[n][0] = make_uint4(kw[0], kw[1], kw[2], kw[3]);
        *(uint4*)&K_lds[n][4] = make_uint4(kw[4], kw[5], kw[6], kw[7]);
        *(uint4*)&V_lds[n][0] = make_uint4(vw[0], vw[1], vw[2], vw[3]);
        *(uint4*)&V_lds[n][4] = make_uint4(vw[4], vw[5], vw[6], vw[7]);
    }
    __syncthreads();

    const int q0base = blockIdx.z * 192 + w * 48;
    bf16x8 qfrag[3];
    bool qin[3];
    int qpix[3];
#pragma unroll
    for (int qt = 0; qt < 3; qt++) {
        int qa = q0base + qt * 16 + qloc;
        int gr = wi * WSZ - PADK + qa / OWSZ, gc = wj * WSZ - PADK + qa % OWSZ;
        bool ib = (gr >= 0 && gr < HH && gc >= 0 && gc < WW);
        qin[qt] = ib;
        qpix[qt] = ib ? gr * WW + gc : 0;
        B8 f;
#pragma unroll
        for (int j = 0; j < 4; j++) f.u[j] = 0;
        if (ib && g < 2) {
            const float* qp = qkvB + (size_t)qpix[qt] * 192 + h * HD + 8 * g;
#pragma unroll
            for (int j = 0; j < 4; j++)
                f.u[j] = cvtpk(qp[2 * j] * QSCALE, qp[2 * j + 1] * QSCALE);
        }
        qfrag[qt] = f.v;
    }

    f32x4 O[3];
    float lsum[3];
#pragma unroll
    for (int qt = 0; qt < 3; qt++) { O[qt] = (f32x4){0.f, 0.f, 0.f, 0.f}; lsum[qt] = 0.f; }
    const f32x4 zz = {0.f, 0.f, 0.f, 0.f};

    for (int step = 0; step < 8; step++) {
        const int k0 = step * 32;
        bf16x8 kfA, kfB;
        if (g < 2) {
            kfA = *(const bf16x8*)&K_lds[k0 + qloc][4 * g];
            kfB = *(const bf16x8*)&K_lds[k0 + 16 + qloc][4 * g];
        } else {
            B8 zf;
#pragma unroll
            for (int j = 0; j < 4; j++) zf.u[j] = 0;
            kfA = zf.v; kfB = zf.v;
        }
        B8 vf;
#pragma unroll
        for (int j = 0; j < 8; j++) {
            int key = k0 + 4 * g + (j & 3) + ((j >> 2) << 4);
            unsigned word = V_lds[key][qloc >> 1];
            vf.s[j] = (short)((qloc & 1) ? (word >> 16) : (word & 0xffff));
        }

#pragma unroll
        for (int qt = 0; qt < 3; qt++) {
            f32x4 sA = __builtin_amdgcn_mfma_f32_16x16x32_bf16(kfA, qfrag[qt], zz, 0, 0, 0);
            f32x4 sB = __builtin_amdgcn_mfma_f32_16x16x32_bf16(kfB, qfrag[qt], zz, 0, 0, 0);
            int qa = q0base + qt * 16 + qloc;
            const float* bpA = biasT + ((size_t)h * NQ1 + k0 + 4 * g) * NKV1 + qa;
            const float* bpB = bpA + 16 * NKV1;
            float pa[4], pb[4];
            float ls = 0.f;
#pragma unroll
            for (int r = 0; r < 4; r++) {
                pa[r] = exp2f(sA[r] + bpA[(size_t)r * NKV1]);
                pb[r] = exp2f(sB[r] + bpB[(size_t)r * NKV1]);
                ls += pa[r] + pb[r];
            }
            B8 pf;
            pf.u[0] = cvtpk(pa[0], pa[1]);
            pf.u[1] = cvtpk(pa[2], pa[3]);
            pf.u[2] = cvtpk(pb[0], pb[1]);
            pf.u[3] = cvtpk(pb[2], pb[3]);
            lsum[qt] += ls;
            O[qt] = __builtin_amdgcn_mfma_f32_16x16x32_bf16(vf.v, pf.v, O[qt], 0, 0, 0);
        }
    }

#pragma unroll
    for (int qt = 0; qt < 3; qt++) {
        float lt = lsum[qt];
        lt += __shfl_xor(lt, 16);
        lt += __shfl_xor(lt, 32);
        float rl = 1.f / lt;
        int qa = q0base + qt * 16 + qloc;
        size_t obase = ((size_t)win * NKV1 + qa) * C2K + h * HD + 4 * g;
        size_t rbase = (size_t)qpix[qt] * 128 + C2K + h * HD + 4 * g;
#pragma unroll
        for (int r = 0; r < 4; r++)
            bb[obase + r] = O[qt][r] * rl + (qin[qt] ? lnx[rbase + r] : 0.f);
    }
}

// ---------------- fold (gather form, no atomics) ----------------
__global__ void fold_kernel(const float* __restrict__ bb, float* __restrict__ folded)
{
    int idx = blockIdx.x * 256 + threadIdx.x;
    if (idx >= 200 * 200 * 64) return;
    int c = idx & 63;
    int j = (idx >> 6) % 200;
    int i = idx / (64 * 200);
    int ilo = (i > 23) ? ((i - 8) >> 4) : 0;
    int ihi = min(11, i >> 4);
    int jlo = (j > 23) ? ((j - 8) >> 4) : 0;
    int jhi = min(11, j >> 4);
    float s = 0.f;
    for (int wi = ilo; wi <= ihi; wi++)
        for (int wj = jlo; wj <= jhi; wj++) {
            int p = (i - wi * 16) * OWSZ + (j - wj * 16);
            s += bb[((size_t)(wi * NWIN + wj) * NKV1 + p) * C2K + c];
        }
    folded[idx] = s;
}

// ---------------- bicubic resize 200->192 ----------------
__device__ __forceinline__ float cubicw(float x)
{
    float ax = fabsf(x);
    const float A = -0.75f;
    if (ax <= 1.f) return ((A + 2.f) * ax - (A + 3.f)) * ax * ax + 1.f;
    if (ax < 2.f)  return A * (ax * (ax * (ax - 5.f) + 8.f) - 4.f);
    return 0.f;
}

__global__ void resize_kernel(const float* __restrict__ folded, float* __restrict__ xcat)
{
    int idx = blockIdx.x * 256 + threadIdx.x;
    if (idx >= HH * WW * C2K) return;
    int c = idx & 63;
    int p = (idx >> 6) % WW;
    int o = idx / (C2K * WW);
    const float ratio = 200.f / 192.f;
    float sr = (o + 0.5f) * ratio - 0.5f;
    float sc = (p + 0.5f) * ratio - 0.5f;
    int fr = (int)floorf(sr), fcc = (int)floorf(sc);
    float wc[4]; int ic[4];
#pragma unroll
    for (int u = 0; u < 4; u++) {
        int jj = fcc - 1 + u;
        wc[u] = cubicw(sc - (float)jj);
        ic[u] = min(max(jj, 0), 199);
    }
    float acc = 0.f;
#pragma unroll
    for (int t = 0; t < 4; t++) {
        int ii = fr - 1 + t;
        float wr = cubicw(sr - (float)ii);
        int ir = min(max(ii, 0), 199);
        const float* rowp = folded + ((size_t)ir * 200) * 64 + c;
        float rs = 0.f;
#pragma unroll
        for (int u = 0; u < 4; u++) rs += wc[u] * rowp[(size_t)ic[u] * 64];
        acc += wr * rs;
    }
    xcat[(size_t)(o * WW + p) * 128 + C2K + c] = acc;
}

// ---------------- MFMA GEMM: C = (A1 [*A2]) @ W + [bias] [+ R], K = 128 ----------------
template<int NTPW>
__launch_bounds__(256)
__global__ void gemm_mfma(const float* __restrict__ A1, int a1s,
                          const float* __restrict__ A2, int a2s,
                          const float* __restrict__ Wm, int ldb,
                          const float* __restrict__ bias,
                          const float* __restrict__ R, int rs,
                          float* __restrict__ C, int cs)
{
    const int tid = threadIdx.x;
    const int lane = tid & 63, w = tid >> 6;
    const int g = lane >> 4, nl = lane & 15;

    bf16x8 wf[NTPW][4];
#pragma unroll
    for (int t = 0; t < NTPW; t++) {
        int ncol = (w * NTPW + t) * 16 + nl;
#pragma unroll
        for (int ks = 0; ks < 4; ks++) {
            const float* wp = Wm + (size_t)(ks * 32 + 8 * g) * ldb + ncol;
            B8 f;
#pragma unroll
            for (int j = 0; j < 4; j++)
                f.u[j] = cvtpk(wp[(size_t)(2 * j) * ldb], wp[(size_t)(2 * j + 1) * ldb]);
            wf[t][ks] = f.v;
        }
    }

    const f32x4 zz = {0.f, 0.f, 0.f, 0.f};
    for (int it = 0; it < 4; it++) {
        const int row = (blockIdx.x * 4 + it) * 16 + nl;
        bf16x8 xf[4];
        const float* ap = A1 + (size_t)row * a1s + 8 * g;
#pragma unroll
        for (int ks = 0; ks < 4; ks++) {
            float4 v0 = *(const float4*)(ap + ks * 32);
            float4 v1 = *(const float4*)(ap + ks * 32 + 4);
            if (A2) {
                const float* ap2 = A2 + (size_t)row * a2s + 8 * g + ks * 32;
                float4 m0 = *(const float4*)(ap2);
                float4 m1 = *(const float4*)(ap2 + 4);
                v0.x *= m0.x; v0.y *= m0.y; v0.z *= m0.z; v0.w *= m0.w;
                v1.x *= m1.x; v1.y *= m1.y; v1.z *= m1.z; v1.w *= m1.w;
            }
            B8 f;
            f.u[0] = cvtpk(v0.x, v0.y);
            f.u[1] = cvtpk(v0.z, v0.w);
            f.u[2] = cvtpk(v1.x, v1.y);
            f.u[3] = cvtpk(v1.z, v1.w);
            xf[ks] = f.v;
        }

        f32x4 acc[NTPW];
#pragma unroll
        for (int t = 0; t < NTPW; t++) acc[t] = zz;
#pragma unroll
        for (int ks = 0; ks < 4; ks++)
#pragma unroll
            for (int t = 0; t < NTPW; t++)
                acc[t] = __builtin_amdgcn_mfma_f32_16x16x32_bf16(wf[t][ks], xf[ks], acc[t], 0, 0, 0);

#pragma unroll
        for (int t = 0; t < NTPW; t++) {
            const int n0t = (w * NTPW + t) * 16 + 4 * g;
            float4 o;
            o.x = acc[t][0]; o.y = acc[t][1]; o.z = acc[t][2]; o.w = acc[t][3];
            if (bias) {
                float4 bv = *(const float4*)(bias + n0t);
                o.x += bv.x; o.y += bv.y; o.z += bv.z; o.w += bv.w;
            }
            if (R) {
                float4 rv = *(const float4*)(R + (size_t)row * rs + n0t);
                o.x += rv.x; o.y += rv.y; o.z += rv.z; o.w += rv.w;
            }
            *(float4*)(C + (size_t)row * cs + n0t) = o;
        }
    }
}

// ---------------- depthwise 3x3 conv ----------------
__global__ void dwconv_kernel(const float* __restrict__ x2n,
                              const float* __restrict__ conv_w,
                              const float* __restrict__ conv_b,
                              float* __restrict__ x2c)
{
    int idx = blockIdx.x * 256 + threadIdx.x;
    if (idx >= NTOK * 128) return;
    int ch = idx & 127, t = idx >> 7;
    int i = t / WW, j = t % WW;
    float acc = conv_b[ch];
#pragma unroll
    for (int a = 0; a < 3; a++) {
        int ii = i + a - 1;
        if (ii < 0 || ii >= HH) continue;
#pragma unroll
        for (int b = 0; b < 3; b++) {
            int jj = j + b - 1;
            if (jj < 0 || jj >= WW) continue;
            acc += conv_w[ch * 9 + a * 3 + b] * x2n[(size_t)(ii * WW + jj) * 256 + ch];
        }
    }
    x2c[(size_t)t * 128 + ch] = acc;
}

extern "C" void kernel_launch(void* const* d_in, const int* in_sizes, int n_in,
                              void* d_out, int out_size, void* d_ws, size_t ws_size,
                              hipStream_t stream)
{
    (void)in_sizes; (void)n_in; (void)out_size; (void)ws_size;
    const float* x_tkn  = (const float*)d_in[0];
    const float* ln1_w  = (const float*)d_in[1];
    const float* ln1_b  = (const float*)d_in[2];
    const float* q1_w   = (const float*)d_in[3];
    const float* kv1_w  = (const float*)d_in[4];
    const float* rpb1   = (const float*)d_in[5];
    const float* q2_w   = (const float*)d_in[6];
    const float* kv2_w  = (const float*)d_in[7];
    const float* rpb2   = (const float*)d_in[8];
    const float* proj_w = (const float*)d_in[9];
    const float* proj_b = (const float*)d_in[10];
    const float* ln2_w  = (const float*)d_in[11];
    const float* ln2_b  = (const float*)d_in[12];
    const float* fc1_w  = (const float*)d_in[13];
    const float* fc1_b  = (const float*)d_in[14];
    const float* sgn_w  = (const float*)d_in[15];
    const float* sgn_b  = (const float*)d_in[16];
    const float* conv_w = (const float*)d_in[17];
    const float* conv_b = (const float*)d_in[18];
    const float* fc2_w  = (const float*)d_in[19];
    const float* fc2_b  = (const float*)d_in[20];
    const int*   rpi    = (const int*)d_in[21];

    float* ws = (float*)d_ws;
    float* lnx    = ws;                 //  0          : 4,718,592  (ln_x; later x_buf)
    float* xcat   = ws + 4718592;       //  4,718,592  : 4,718,592  (x_cat; later x2c)
    float* bbuf   = ws + 9437184;       //  9,437,184  : 5,308,416  (bb; later y)
    float* bias1T = ws + 14745600;      // 14,745,600  : 2,359,296
    float* bias2T = ws + 17104896;      // 17,104,896  :   589,824
    float* wcomb  = ws + 17694720;      // 17,694,720  :    49,152
    float* qkv    = ws + 17743872;      // 17,743,872  : 7,077,888  (qkvA then qkvB)
    float* foldp  = ws + 17743872;      // aliases qkv (qkv dead after attn2)
    float* h1     = ws + 14745600;      // aliases bias/wcomb/qkv (all dead by fc1)
    float* out    = (float*)d_out;

    // 1. LN1
    ln_kernel<<<NTOK / 4, 256, 0, stream>>>(x_tkn, 128, 0, lnx, 128, 0, ln1_w, ln1_b, NTOK);
    // 2. combined weight + bias transposes
    wcomb_kernel<<<(128 * 384 + 255) / 256, 256, 0, stream>>>(q1_w, kv1_w, q2_w, kv2_w, wcomb);
    bias1_kernel<<<(H2K * NKV1 * NQ1) / 256, 256, 0, stream>>>(rpb1, rpi, bias1T);
    bias2_kernel<<<(H2K * NQ1 * NKV1) / 256, 256, 0, stream>>>(rpb2, rpi, bias2T);
    // 3. qkvA = lnx @ Wcomb[:, 0:192]
    gemm_mfma<3><<<NTOK / 64, 256, 0, stream>>>(lnx, 128, nullptr, 0, wcomb, 384,
                                                nullptr, nullptr, 0, qkv, 192);
    // 4. attn1 -> xcat[:, 0:64] (+xa residual)
    attn1_mfma<<<dim3(144, 4, 2), 256, 0, stream>>>(qkv, lnx, bias1T, xcat);
    // 5. qkvB = lnx @ Wcomb[:, 192:384]
    gemm_mfma<3><<<NTOK / 64, 256, 0, stream>>>(lnx, 128, nullptr, 0, wcomb + 192, 384,
                                                nullptr, nullptr, 0, qkv, 192);
    // 6. attn2 -> bb (+xb_p residual)
    attn2_mfma<<<dim3(144, 4, 3), 256, 0, stream>>>(qkv, lnx, bias2T, bbuf);
    // 7. fold bb -> folded (200x200x64)
    fold_kernel<<<(200 * 200 * 64) / 256, 256, 0, stream>>>(bbuf, foldp);
    // 8. bicubic resize -> xcat[:, 64:128]
    resize_kernel<<<(HH * WW * C2K) / 256, 256, 0, stream>>>(foldp, xcat);
    // 9. proj: x_buf = xcat @ proj_w + proj_b + x_tkn
    gemm_mfma<2><<<NTOK / 64, 256, 0, stream>>>(xcat, 128, nullptr, 0, proj_w, 128,
                                                proj_b, x_tkn, 128, lnx, 128);
    // 10. LN2: y = LN(x_buf)
    ln_kernel<<<NTOK / 4, 256, 0, stream>>>(lnx, 128, 0, bbuf, 128, 0, ln2_w, ln2_b, NTOK);
    // 11. fc1: h1 = y @ fc1_w + fc1_b  (N=256)
    gemm_mfma<4><<<NTOK / 64, 256, 0, stream>>>(bbuf, 128, nullptr, 0, fc1_w, 256,
                                                fc1_b, nullptr, 0, h1, 256);
    // 12. sgn LN on x2 half of h1 (in place)
    ln_kernel<<<NTOK / 4, 256, 0, stream>>>(h1, 256, 128, h1, 256, 128, sgn_w, sgn_b, NTOK);
    // 13. depthwise conv: x2c = dwconv(x2n)
    dwconv_kernel<<<(NTOK * 128) / 256, 256, 0, stream>>>(h1 + 128, conv_w, conv_b, xcat);
    // 14. fc2: out = (x1 * x2c) @ fc2_w + fc2_b + x_buf
    gemm_mfma<2><<<NTOK / 64, 256, 0, stream>>>(h1, 256, xcat, 128, fc2_w, 128,
                                                fc2_b, lnx, 128, out, 128);
}